// Round 5
// baseline (231.261 us; speedup 1.0000x reference)
//
#include <hip/hip_runtime.h>
#include <hip/hip_bf16.h>

typedef __attribute__((ext_vector_type(8))) short short8;
typedef __attribute__((ext_vector_type(4))) float f32x4;
typedef __attribute__((ext_vector_type(16))) float f32x16;
typedef __attribute__((ext_vector_type(4))) unsigned u32x4;

#define LOG2E 1.44269504f
#define SCL2  0.18033688f   // 0.125 * log2(e)
#define MNEG  -3.0e38f

__device__ __forceinline__ short f2bf(float f) {
  union { float f; unsigned u; } x; x.f = f;
  return (short)((x.u + 0x7FFFu + ((x.u >> 16) & 1u)) >> 16);  // RNE
}
__device__ __forceinline__ float exp2g(float x) {
  float r; asm("v_exp_f32 %0, %1" : "=v"(r) : "v"(x)); return r;
}
__device__ __forceinline__ unsigned cvt_pk_bf16(float lo, float hi) {
  unsigned r;
  asm("v_cvt_pk_bf16_f32 %0, %1, %2" : "=v"(r) : "v"(lo), "v"(hi));
  return r;
}

// ---------------- prepass: fp32 -> bf16 K with token padding ----------------
__global__ __launch_bounds__(256) void convk_kernel(
    const float* __restrict__ src, short* __restrict__ dst,
    int Tin, int pad, int total_chunks) {
  int cid = blockIdx.x * 256 + threadIdx.x;
  if (cid >= total_chunks) return;
  int Tpad = Tin + 2 * pad;
  int row = cid >> 3;
  int d0 = (cid & 7) * 8;
  int tok = row % Tpad;
  int nh = row / Tpad;
  int st = tok - pad;
  short8 o;
  if (st >= 0 && st < Tin) {
    const float4* sp = (const float4*)(src + ((size_t)nh * Tin + st) * 64 + d0);
    float4 f0 = sp[0], f1 = sp[1];
    o[0] = f2bf(f0.x); o[1] = f2bf(f0.y); o[2] = f2bf(f0.z); o[3] = f2bf(f0.w);
    o[4] = f2bf(f1.x); o[5] = f2bf(f1.y); o[6] = f2bf(f1.z); o[7] = f2bf(f1.w);
  } else {
#pragma unroll
    for (int j = 0; j < 8; ++j) o[j] = 0;
  }
  *(short8*)(dst + (size_t)row * 64 + d0) = o;
}

// ---------------- prepass: fp32 V -> bf16 V^T [nh][64][Tpad] ----------------
__global__ __launch_bounds__(256) void transv_kernel(
    const float* __restrict__ src, short* __restrict__ dst,
    int Tin, int pad, int tiles) {
  int tile = blockIdx.x % tiles;
  int nh = blockIdx.x / tiles;
  int Tpad = Tin + 2 * pad;
  int c0 = tile * 64;
  __shared__ short lt[64][72];
  int tid = threadIdx.x;
  int tok = tid >> 2;
  int dc = (tid & 3) * 16;
  int st = c0 + tok - pad;
  if (st >= 0 && st < Tin) {
    const float4* sp = (const float4*)(src + ((size_t)nh * Tin + st) * 64 + dc);
#pragma unroll
    for (int i = 0; i < 4; ++i) {
      float4 f = sp[i];
      lt[tok][dc + i * 4 + 0] = f2bf(f.x);
      lt[tok][dc + i * 4 + 1] = f2bf(f.y);
      lt[tok][dc + i * 4 + 2] = f2bf(f.z);
      lt[tok][dc + i * 4 + 3] = f2bf(f.w);
    }
  } else {
#pragma unroll
    for (int i = 0; i < 16; ++i) lt[tok][dc + i] = 0;
  }
  __syncthreads();
  int d = tid >> 2;
  int tc = (tid & 3) * 16;
  short8 o0, o1;
#pragma unroll
  for (int j = 0; j < 8; ++j) { o0[j] = lt[tc + j][d]; o1[j] = lt[tc + 8 + j][d]; }
  short* dp = dst + ((size_t)nh * 64 + d) * Tpad + c0 + tc;
  *(short8*)(dp) = o0;
  *(short8*)(dp + 8) = o1;
}

// ---------------- prepass: masks padded + pre-scaled by log2(e) -------------
__global__ __launch_bounds__(256) void maskk_kernel(
    const float* __restrict__ am, const float* __restrict__ sm,
    const float* __restrict__ gm,
    float* __restrict__ am2, float* __restrict__ sm2, float* __restrict__ gm2) {
  int i = blockIdx.x * 256 + threadIdx.x;
  if (i < 2 * 4352) {
    int n = i / 4352, r = i % 4352, s = r - 128;
    am2[i] = (s >= 0 && s < 4096) ? am[n * 4096 + s] * LOG2E : MNEG;
  } else if (i < 2 * 4352 + 2 * 1344) {
    int j = i - 2 * 4352;
    int n = j / 1344, r = j % 1344, s = r - 160;
    sm2[j] = (s >= 0 && s < 1024) ? sm[n * 1024 + s] * LOG2E : MNEG;
  } else if (i < 2 * 4352 + 2 * 1344 + 2 * 64) {
    int j = i - 2 * 4352 - 2 * 1344;
    gm2[j] = gm[j] * LOG2E;
  }
}

// ---------------- main attention kernel (swapped-QK 32x32, in-reg softmax) --
// 4 waves / 256 threads per (n,h,block); wave owns 32 queries (q = lane&31).
// 11 tiles of 64 keys: tile0 global | 1-4 sparse | 5-10 local.
// QK^T computed swapped: pacc[kb][reg] = S[key=crow(reg,hi)+32kb][q],
// crow(r,hi) = (r&3)+8*(r>>2)+4*hi. Softmax scalar per lane (m,l), P packed
// via cvt_pk + shfl_xor(32) into PV A-fragments. No P LDS round-trip.
__global__ __launch_bounds__(256, 4) void lsg_attn4(
    const short* __restrict__ KL, const short* __restrict__ VTL,
    const short* __restrict__ KS, const short* __restrict__ VTS,
    const short* __restrict__ KG, const short* __restrict__ VTG,
    const float* __restrict__ AM2, const float* __restrict__ SM2,
    const float* __restrict__ GM2,
    const float* __restrict__ q_, float* __restrict__ out) {
  constexpr int TPL = 4352, TPS = 1344;
  __shared__ __align__(16) short k_lds[2][64][72];
  __shared__ __align__(16) short v_lds[2][64][72];
  __shared__ __align__(16) float m_f[2][64];
  __shared__ __align__(16) float scl[4][32];

  int bid = blockIdx.x;
  bid = (bid & 7) * 96 + (bid >> 3);        // XCD-contiguous logical ids
  const int b = bid & 31, nh = bid >> 5, n_ = nh / 12;
  const int tid = threadIdx.x;
  const int wid = tid >> 6, lane = tid & 63;
  const int q32 = lane & 31, hi = lane >> 5;
  const int r = tid >> 2, ch = tid & 3;     // staging: 64 rows x 4 chunks(32B)

  // ---- Q fragments (B-operand): qa[m] = Q[q32][m*16 + hi*8 .. +7] ----
  const float* qb = q_ + ((size_t)nh * 4096 + b * 128 + wid * 32 + q32) * 64;
  short8 qa[4];
#pragma unroll
  for (int m = 0; m < 4; ++m) {
    const float* qp = qb + m * 16 + hi * 8;
    float4 f0 = *(const float4*)qp;
    float4 f1 = *(const float4*)(qp + 4);
    u32x4 u;
    u[0] = cvt_pk_bf16(f0.x, f0.y);
    u[1] = cvt_pk_bf16(f0.z, f0.w);
    u[2] = cvt_pk_bf16(f1.x, f1.y);
    u[3] = cvt_pk_bf16(f1.z, f1.w);
    qa[m] = __builtin_bit_cast(short8, u);
  }

  f32x16 acc0, acc1;
#pragma unroll
  for (int i = 0; i < 16; ++i) { acc0[i] = 0.f; acc1[i] = 0.f; }
  float mrun = 0.f, lrun = 0.f;

  auto src_for = [&](int t, const short*& kp, const short*& vp,
                     const float*& mp, int& stride) {
    if (t == 0) {
      kp = KG + (size_t)nh * (64 * 64);
      vp = VTG + (size_t)nh * (64 * 64);
      mp = GM2 + n_ * 64;
      stride = 64;
    } else if (t <= 4) {
      int r0 = b * 32 + (t - 1) * 64 + (t >= 3 ? 96 : 0);
      kp = KS + ((size_t)nh * TPS + r0) * 64;
      vp = VTS + (size_t)nh * (64 * TPS) + r0;
      mp = SM2 + n_ * TPS + r0;
      stride = TPS;
    } else {
      int r0 = b * 128 + (t - 5) * 64;
      kp = KL + ((size_t)nh * TPL + r0) * 64;
      vp = VTL + (size_t)nh * (64 * TPL) + r0;
      mp = AM2 + n_ * TPL + r0;
      stride = TPL;
    }
  };

  short8 kr0, kr1, vr0, vr1;
  float mr = MNEG;

  // ---- prologue: tile0 -> buf0 directly; tile1 -> regs ----
  {
    const short* kp; const short* vp; const float* mp; int st;
    src_for(0, kp, vp, mp, st);
    kr0 = *(const short8*)(kp + r * 64 + ch * 16);
    kr1 = *(const short8*)(kp + r * 64 + ch * 16 + 8);
    vr0 = *(const short8*)(vp + (size_t)r * st + ch * 16);
    vr1 = *(const short8*)(vp + (size_t)r * st + ch * 16 + 8);
    *(short8*)(&k_lds[0][r][ch * 16]) = kr0;
    *(short8*)(&k_lds[0][r][ch * 16 + 8]) = kr1;
    *(short8*)(&v_lds[0][r][ch * 16]) = vr0;
    *(short8*)(&v_lds[0][r][ch * 16 + 8]) = vr1;
    if (tid < 64) m_f[0][tid] = mp[tid];
    src_for(1, kp, vp, mp, st);
    kr0 = *(const short8*)(kp + r * 64 + ch * 16);
    kr1 = *(const short8*)(kp + r * 64 + ch * 16 + 8);
    vr0 = *(const short8*)(vp + (size_t)r * st + ch * 16);
    vr1 = *(const short8*)(vp + (size_t)r * st + ch * 16 + 8);
    if (tid < 64) mr = mp[tid];
  }

  for (int t = 0; t < 11; ++t) {
    __syncthreads();
    const int cur = t & 1, nxt = cur ^ 1;
    if (t < 10) {   // write staged tile t+1
      *(short8*)(&k_lds[nxt][r][ch * 16]) = kr0;
      *(short8*)(&k_lds[nxt][r][ch * 16 + 8]) = kr1;
      *(short8*)(&v_lds[nxt][r][ch * 16]) = vr0;
      *(short8*)(&v_lds[nxt][r][ch * 16 + 8]) = vr1;
      if (tid < 64) m_f[nxt][tid] = mr;
    }
    if (t < 9) {    // prefetch tile t+2 into regs
      const short* kp; const short* vp; const float* mp; int st;
      src_for(t + 2, kp, vp, mp, st);
      kr0 = *(const short8*)(kp + r * 64 + ch * 16);
      kr1 = *(const short8*)(kp + r * 64 + ch * 16 + 8);
      vr0 = *(const short8*)(vp + (size_t)r * st + ch * 16);
      vr1 = *(const short8*)(vp + (size_t)r * st + ch * 16 + 8);
      if (tid < 64) mr = mp[tid];
    }

    // ---- QK^T swapped: pacc[kb] = K[32kb..+31] . Q  (D: row=key, col=q) ----
    const short* kb0 = &k_lds[cur][q32][0];
    const short* kb1 = &k_lds[cur][32 + q32][0];
    f32x16 pacc0, pacc1;
    {
      f32x16 zz = {};
      short8 ka;
      ka = *(const short8*)(kb0 + 0 * 16 + hi * 8);
      pacc0 = __builtin_amdgcn_mfma_f32_32x32x16_bf16(ka, qa[0], zz, 0, 0, 0);
      ka = *(const short8*)(kb0 + 1 * 16 + hi * 8);
      pacc0 = __builtin_amdgcn_mfma_f32_32x32x16_bf16(ka, qa[1], pacc0, 0, 0, 0);
      ka = *(const short8*)(kb0 + 2 * 16 + hi * 8);
      pacc0 = __builtin_amdgcn_mfma_f32_32x32x16_bf16(ka, qa[2], pacc0, 0, 0, 0);
      ka = *(const short8*)(kb0 + 3 * 16 + hi * 8);
      pacc0 = __builtin_amdgcn_mfma_f32_32x32x16_bf16(ka, qa[3], pacc0, 0, 0, 0);
      ka = *(const short8*)(kb1 + 0 * 16 + hi * 8);
      pacc1 = __builtin_amdgcn_mfma_f32_32x32x16_bf16(ka, qa[0], zz, 0, 0, 0);
      ka = *(const short8*)(kb1 + 1 * 16 + hi * 8);
      pacc1 = __builtin_amdgcn_mfma_f32_32x32x16_bf16(ka, qa[1], pacc1, 0, 0, 0);
      ka = *(const short8*)(kb1 + 2 * 16 + hi * 8);
      pacc1 = __builtin_amdgcn_mfma_f32_32x32x16_bf16(ka, qa[2], pacc1, 0, 0, 0);
      ka = *(const short8*)(kb1 + 3 * 16 + hi * 8);
      pacc1 = __builtin_amdgcn_mfma_f32_32x32x16_bf16(ka, qa[3], pacc1, 0, 0, 0);
    }

    // ---- mask + scale + exp2 (defer-max, log2 domain) ----
    f32x4 p0q[4], p1q[4];
    float rs = 0.f;
#pragma unroll
    for (int q2 = 0; q2 < 4; ++q2) {
      f32x4 mk0 = *(const f32x4*)&m_f[cur][8 * q2 + 4 * hi];
      f32x4 mk1 = *(const f32x4*)&m_f[cur][32 + 8 * q2 + 4 * hi];
#pragma unroll
      for (int i = 0; i < 4; ++i) {
        float p0 = exp2g(fmaf(pacc0[4 * q2 + i], SCL2, mk0[i]) - mrun);
        float p1 = exp2g(fmaf(pacc1[4 * q2 + i], SCL2, mk1[i]) - mrun);
        p0q[q2][i] = p0;
        p1q[q2][i] = p1;
        rs += p0 + p1;
      }
    }

    if (__any(rs > 4096.f)) {   // rare: rescale multiplicatively, no s needed
      float pmax = 0.f;
#pragma unroll
      for (int q2 = 0; q2 < 4; ++q2)
#pragma unroll
        for (int i = 0; i < 4; ++i)
          pmax = fmaxf(pmax, fmaxf(p0q[q2][i], p1q[q2][i]));
      pmax = fmaxf(pmax, __shfl_xor(pmax, 32));
      float pm = fmaxf(pmax, 1.0f);
      float sc = 1.0f / pm;       // uniform across (lane, lane+32) pair
      mrun += __log2f(pm);
#pragma unroll
      for (int q2 = 0; q2 < 4; ++q2) { p0q[q2] *= sc; p1q[q2] *= sc; }
      rs *= sc;
      lrun = lrun * sc + rs;
      scl[wid][q32] = sc;         // redistribute per-query scale to D-layout
#pragma unroll
      for (int q2 = 0; q2 < 4; ++q2) {
        f32x4 s4 = *(const f32x4*)&scl[wid][8 * q2 + 4 * hi];
#pragma unroll
        for (int i = 0; i < 4; ++i) {
          acc0[4 * q2 + i] *= s4[i];
          acc1[4 * q2 + i] *= s4[i];
        }
      }
    } else {
      lrun += rs;
    }

    // ---- pack P to bf16 pairs (consecutive keys are lane-local) ----
    unsigned w0[4][2], w1[4][2];
#pragma unroll
    for (int q2 = 0; q2 < 4; ++q2) {
      w0[q2][0] = cvt_pk_bf16(p0q[q2][0], p0q[q2][1]);
      w0[q2][1] = cvt_pk_bf16(p0q[q2][2], p0q[q2][3]);
      w1[q2][0] = cvt_pk_bf16(p1q[q2][0], p1q[q2][1]);
      w1[q2][1] = cvt_pk_bf16(p1q[q2][2], p1q[q2][3]);
    }

    // ---- PV: acc[dh] += P(32q x 16k) * V(16k x 32d), 4 key-blocks ----
    const short* vb0 = &v_lds[cur][q32][0];        // d row (dh=0)
    const short* vb1 = &v_lds[cur][32 + q32][0];   // d row (dh=1)
#define PVSTEP(W, KBB)                                                        \
    {                                                                         \
      const int q2a = 2 * ((KBB) & 1), q2b = q2a + 1;                         \
      unsigned xa0 = __shfl_xor(W[q2a][0], 32);                               \
      unsigned xa1 = __shfl_xor(W[q2a][1], 32);                               \
      unsigned xb0 = __shfl_xor(W[q2b][0], 32);                               \
      unsigned xb1 = __shfl_xor(W[q2b][1], 32);                               \
      u32x4 u;                                                                \
      u[0] = hi ? xb0 : W[q2a][0];                                            \
      u[1] = hi ? xb1 : W[q2a][1];                                            \
      u[2] = hi ? W[q2b][0] : xa0;                                            \
      u[3] = hi ? W[q2b][1] : xa1;                                            \
      short8 pa = __builtin_bit_cast(short8, u);                              \
      short8 vl = *(const short8*)(vb0 + (KBB) * 16 + hi * 8);                \
      short8 vh = *(const short8*)(vb1 + (KBB) * 16 + hi * 8);                \
      acc0 = __builtin_amdgcn_mfma_f32_32x32x16_bf16(pa, vl, acc0, 0, 0, 0);  \
      acc1 = __builtin_amdgcn_mfma_f32_32x32x16_bf16(pa, vh, acc1, 0, 0, 0);  \
    }
    PVSTEP(w0, 0)
    PVSTEP(w0, 1)
    PVSTEP(w1, 2)
    PVSTEP(w1, 3)
#undef PVSTEP
  }

  // ---- epilogue: combine l across lane pair, normalize, store ----
  float l = lrun + __shfl_xor(lrun, 32);
  scl[wid][q32] = 1.0f / l;
  float* ob = out + ((size_t)nh * 4096 + b * 128 + wid * 32) * 64 + q32;
#pragma unroll
  for (int q2 = 0; q2 < 4; ++q2) {
    f32x4 li = *(const f32x4*)&scl[wid][8 * q2 + 4 * hi];
#pragma unroll
    for (int i = 0; i < 4; ++i) {
      int row = 8 * q2 + 4 * hi + i;
      ob[(size_t)row * 64]      = acc0[4 * q2 + i] * li[i];
      ob[(size_t)row * 64 + 32] = acc1[4 * q2 + i] * li[i];
    }
  }
}

// ---------------- fallback (round-1 kernel, used if ws too small) -----------
__global__ __launch_bounds__(256) void lsg_attn_fb(
    const float* __restrict__ q_,  const float* __restrict__ k_,
    const float* __restrict__ v_,  const float* __restrict__ amask,
    const float* __restrict__ sk,  const float* __restrict__ sv,
    const float* __restrict__ smk, const float* __restrict__ gk,
    const float* __restrict__ gv,  const float* __restrict__ gmk,
    float* __restrict__ out) {
  constexpr int T = 4096, D = 64, TS = 1024;
  constexpr float NEGF = -3.402823466e38f;
  __shared__ __align__(16) short k_lds[32][72];
  __shared__ __align__(16) short v_lds[64][40];
  __shared__ __align__(16) short p_lds[4][32][40];
  __shared__ float m_lds[32];
  const int bid = blockIdx.x;
  const int b = bid & 31, nh = bid >> 5, n_ = nh / 12;
  const int tid = threadIdx.x, wid = tid >> 6, lane = tid & 63;
  const int c = lane & 15, g = lane >> 4;
  const float* qb = q_ + ((size_t)nh * T + (size_t)b * 128) * D;
  const float* kb = k_ + (size_t)nh * T * D;
  const float* vb = v_ + (size_t)nh * T * D;
  const float* skb = sk + (size_t)nh * TS * D;
  const float* svb = sv + (size_t)nh * TS * D;
  const float* gkb = gk + (size_t)nh * 64 * D;
  const float* gvb = gv + (size_t)nh * 64 * D;
  const float* am = amask + (size_t)n_ * T;
  const float* sm = smk + (size_t)n_ * TS;
  const float* gm = gmk + (size_t)n_ * 64;
  short8 qa[2][2];
#pragma unroll
  for (int mt = 0; mt < 2; ++mt)
#pragma unroll
    for (int kc = 0; kc < 2; ++kc) {
      const float* qp = qb + (size_t)(wid * 32 + mt * 16 + c) * D + kc * 32 + g * 8;
      short8 t;
#pragma unroll
      for (int j = 0; j < 8; ++j) t[j] = f2bf(qp[j]);
      qa[mt][kc] = t;
    }
  f32x4 acc[2][4];
#pragma unroll
  for (int mt = 0; mt < 2; ++mt)
#pragma unroll
    for (int dd = 0; dd < 4; ++dd) acc[mt][dd] = f32x4{0.f, 0.f, 0.f, 0.f};
  float mrun[2][4], lrun[2][4];
#pragma unroll
  for (int mt = 0; mt < 2; ++mt)
#pragma unroll
    for (int j = 0; j < 4; ++j) { mrun[mt][j] = NEGF; lrun[mt][j] = 0.f; }
  const int key_local = tid >> 3;
  const int seg = tid & 7;
  const int d0 = seg * 8;
  for (int tile = 0; tile < 22; ++tile) {
    __syncthreads();
    {
      const int kk = tile * 32 + key_local;
      const float* ksrc; const float* vsrc; float mval; bool valid;
      if (kk < 64) {
        ksrc = gkb + kk * D; vsrc = gvb + kk * D; mval = gm[kk]; valid = true;
      } else if (kk < 320) {
        int s = b * 32 - 160 + (kk - 64) + ((kk >= 192) ? 96 : 0);
        valid = (s >= 0) && (s < TS);
        int sc2 = valid ? s : 0;
        ksrc = skb + sc2 * D; vsrc = svb + sc2 * D;
        mval = valid ? sm[sc2] : NEGF;
      } else {
        int tt = b * 128 - 128 + (kk - 320);
        valid = (tt >= 0) && (tt < T);
        int tc = valid ? tt : 0;
        ksrc = kb + tc * D; vsrc = vb + tc * D;
        mval = valid ? am[tc] : NEGF;
      }
      short8 k8; short v8[8];
      if (valid) {
#pragma unroll
        for (int j = 0; j < 8; ++j) { k8[j] = f2bf(ksrc[d0 + j]); v8[j] = f2bf(vsrc[d0 + j]); }
      } else {
#pragma unroll
        for (int j = 0; j < 8; ++j) { k8[j] = 0; v8[j] = 0; }
      }
      *(short8*)(&k_lds[key_local][d0]) = k8;
#pragma unroll
      for (int j = 0; j < 8; ++j) v_lds[d0 + j][key_local] = v8[j];
      if (seg == 0) m_lds[key_local] = mval;
    }
    __syncthreads();
    short8 bk[2][2];
#pragma unroll
    for (int kt = 0; kt < 2; ++kt)
#pragma unroll
      for (int kc = 0; kc < 2; ++kc)
        bk[kt][kc] = *(const short8*)(&k_lds[kt * 16 + c][kc * 32 + g * 8]);
    f32x4 s_[2][2];
#pragma unroll
    for (int mt = 0; mt < 2; ++mt)
#pragma unroll
      for (int kt = 0; kt < 2; ++kt) {
        f32x4 z = f32x4{0.f, 0.f, 0.f, 0.f};
        z = __builtin_amdgcn_mfma_f32_16x16x32_bf16(qa[mt][0], bk[kt][0], z, 0, 0, 0);
        z = __builtin_amdgcn_mfma_f32_16x16x32_bf16(qa[mt][1], bk[kt][1], z, 0, 0, 0);
        s_[mt][kt] = z;
      }
    const float msk0 = m_lds[c];
    const float msk1 = m_lds[16 + c];
#pragma unroll
    for (int mt = 0; mt < 2; ++mt) {
#pragma unroll
      for (int j = 0; j < 4; ++j) {
        float s0 = s_[mt][0][j] * 0.125f + msk0;
        float s1 = s_[mt][1][j] * 0.125f + msk1;
        float tv = fmaxf(s0, s1);
        tv = fmaxf(tv, __shfl_xor(tv, 1));
        tv = fmaxf(tv, __shfl_xor(tv, 2));
        tv = fmaxf(tv, __shfl_xor(tv, 4));
        tv = fmaxf(tv, __shfl_xor(tv, 8));
        float mold = mrun[mt][j];
        float mnew = fmaxf(mold, tv);
        float scale = __expf(mold - mnew);
        mrun[mt][j] = mnew;
        float p0 = __expf(s0 - mnew);
        float p1 = __expf(s1 - mnew);
        lrun[mt][j] = lrun[mt][j] * scale + p0 + p1;
#pragma unroll
        for (int dd = 0; dd < 4; ++dd) acc[mt][dd][j] *= scale;
        p_lds[wid][mt * 16 + g * 4 + j][c] = f2bf(p0);
        p_lds[wid][mt * 16 + g * 4 + j][16 + c] = f2bf(p1);
      }
    }
    __syncthreads();
#pragma unroll
    for (int mt = 0; mt < 2; ++mt) {
      short8 pa = *(const short8*)(&p_lds[wid][mt * 16 + c][g * 8]);
#pragma unroll
      for (int dd = 0; dd < 4; ++dd) {
        short8 bv = *(const short8*)(&v_lds[dd * 16 + c][g * 8]);
        acc[mt][dd] = __builtin_amdgcn_mfma_f32_16x16x32_bf16(pa, bv, acc[mt][dd], 0, 0, 0);
      }
    }
  }
  float* ob = out + ((size_t)nh * T + (size_t)b * 128 + (size_t)wid * 32) * D;
#pragma unroll
  for (int mt = 0; mt < 2; ++mt)
#pragma unroll
    for (int j = 0; j < 4; ++j) {
      float l = lrun[mt][j];
      l += __shfl_xor(l, 1);
      l += __shfl_xor(l, 2);
      l += __shfl_xor(l, 4);
      l += __shfl_xor(l, 8);
      float inv = 1.f / l;
      int row = mt * 16 + g * 4 + j;
#pragma unroll
      for (int dd = 0; dd < 4; ++dd)
        ob[(size_t)row * D + dd * 16 + c] = acc[mt][dd][j] * inv;
    }
}

extern "C" void kernel_launch(void* const* d_in, const int* in_sizes, int n_in,
                              void* d_out, int out_size, void* d_ws, size_t ws_size,
                              hipStream_t stream) {
  const float* q  = (const float*)d_in[0];
  const float* k  = (const float*)d_in[1];
  const float* v  = (const float*)d_in[2];
  const float* am = (const float*)d_in[3];
  const float* sk = (const float*)d_in[4];
  const float* sv = (const float*)d_in[5];
  const float* sm = (const float*)d_in[6];
  const float* gk = (const float*)d_in[7];
  const float* gv = (const float*)d_in[8];
  const float* gm = (const float*)d_in[9];
  float* out = (float*)d_out;

  size_t off = 0;
  char* base = (char*)d_ws;
  auto alloc = [&](size_t bytes) { void* p = base + off; off += bytes; return p; };
  short* KL  = (short*)alloc(13369344);  // [24][4352][64] bf16
  short* VTL = (short*)alloc(13369344);  // [24][64][4352]
  short* KS  = (short*)alloc(4128768);   // [24][1344][64]
  short* VTS = (short*)alloc(4128768);   // [24][64][1344]
  short* KG  = (short*)alloc(196608);    // [24][64][64]
  short* VTG = (short*)alloc(196608);    // [24][64][64]
  float* AM2 = (float*)alloc(34816);     // [2][4352]
  float* SM2 = (float*)alloc(10752);     // [2][1344]
  float* GM2 = (float*)alloc(512);       // [2][64]

  if (off <= ws_size) {
    hipLaunchKernelGGL(convk_kernel, dim3(3264), dim3(256), 0, stream, k,  KL, 4096, 128, 24 * 4352 * 8);
    hipLaunchKernelGGL(convk_kernel, dim3(1008), dim3(256), 0, stream, sk, KS, 1024, 160, 24 * 1344 * 8);
    hipLaunchKernelGGL(convk_kernel, dim3(48),   dim3(256), 0, stream, gk, KG, 64,   0,   24 * 64 * 8);
    hipLaunchKernelGGL(transv_kernel, dim3(24 * 68), dim3(256), 0, stream, v,  VTL, 4096, 128, 68);
    hipLaunchKernelGGL(transv_kernel, dim3(24 * 21), dim3(256), 0, stream, sv, VTS, 1024, 160, 21);
    hipLaunchKernelGGL(transv_kernel, dim3(24),      dim3(256), 0, stream, gv, VTG, 64,   0,   1);
    hipLaunchKernelGGL(maskk_kernel, dim3(45), dim3(256), 0, stream, am, sm, gm, AM2, SM2, GM2);
    hipLaunchKernelGGL(lsg_attn4, dim3(768), dim3(256), 0, stream,
                       KL, VTL, KS, VTS, KG, VTG, AM2, SM2, GM2, q, out);
  } else {
    hipLaunchKernelGGL(lsg_attn_fb, dim3(768), dim3(256), 0, stream,
                       q, k, v, am, sk, sv, sm, gk, gv, gm, out);
  }
}

// Round 6
// 71.761 us; speedup vs baseline: 3.2226x; 3.2226x over previous
//
#include <hip/hip_runtime.h>
#include <hip/hip_bf16.h>

typedef __attribute__((ext_vector_type(8))) short short8;
typedef __attribute__((ext_vector_type(4))) float f32x4;

#define LOG2E 1.44269504f
#define SCL2  0.18033688f   // 0.125 * log2(e)
#define MNEG  -3.0e38f
#define MINIT -1.0e30f

__device__ __forceinline__ short f2bf(float f) {
  union { float f; unsigned u; } x; x.f = f;
  return (short)((x.u + 0x7FFFu + ((x.u >> 16) & 1u)) >> 16);  // RNE
}
__device__ __forceinline__ float exp2g(float x) {
  float r; asm("v_exp_f32 %0, %1" : "=v"(r) : "v"(x)); return r;
}
__device__ __forceinline__ unsigned cvt_pk_bf16(float lo, float hi) {
  unsigned r;
  asm("v_cvt_pk_bf16_f32 %0, %1, %2" : "=v"(r) : "v"(lo), "v"(hi));
  return r;
}

// ---------------- prepass: fp32 -> bf16 K with token padding ----------------
__global__ __launch_bounds__(256) void convk_kernel(
    const float* __restrict__ src, short* __restrict__ dst,
    int Tin, int pad, int total_chunks) {
  int cid = blockIdx.x * 256 + threadIdx.x;
  if (cid >= total_chunks) return;
  int Tpad = Tin + 2 * pad;
  int row = cid >> 3;
  int d0 = (cid & 7) * 8;
  int tok = row % Tpad;
  int nh = row / Tpad;
  int st = tok - pad;
  short8 o;
  if (st >= 0 && st < Tin) {
    const float4* sp = (const float4*)(src + ((size_t)nh * Tin + st) * 64 + d0);
    float4 f0 = sp[0], f1 = sp[1];
    o[0] = f2bf(f0.x); o[1] = f2bf(f0.y); o[2] = f2bf(f0.z); o[3] = f2bf(f0.w);
    o[4] = f2bf(f1.x); o[5] = f2bf(f1.y); o[6] = f2bf(f1.z); o[7] = f2bf(f1.w);
  } else {
#pragma unroll
    for (int j = 0; j < 8; ++j) o[j] = 0;
  }
  *(short8*)(dst + (size_t)row * 64 + d0) = o;
}

// ---------------- prepass: fp32 V -> bf16 V^T [nh][64][Tpad] ----------------
__global__ __launch_bounds__(256) void transv_kernel(
    const float* __restrict__ src, short* __restrict__ dst,
    int Tin, int pad, int tiles) {
  int tile = blockIdx.x % tiles;
  int nh = blockIdx.x / tiles;
  int Tpad = Tin + 2 * pad;
  int c0 = tile * 64;
  __shared__ short lt[64][72];
  int tid = threadIdx.x;
  int tok = tid >> 2;
  int dc = (tid & 3) * 16;
  int st = c0 + tok - pad;
  if (st >= 0 && st < Tin) {
    const float4* sp = (const float4*)(src + ((size_t)nh * Tin + st) * 64 + dc);
#pragma unroll
    for (int i = 0; i < 4; ++i) {
      float4 f = sp[i];
      lt[tok][dc + i * 4 + 0] = f2bf(f.x);
      lt[tok][dc + i * 4 + 1] = f2bf(f.y);
      lt[tok][dc + i * 4 + 2] = f2bf(f.z);
      lt[tok][dc + i * 4 + 3] = f2bf(f.w);
    }
  } else {
#pragma unroll
    for (int i = 0; i < 16; ++i) lt[tok][dc + i] = 0;
  }
  __syncthreads();
  int d = tid >> 2;
  int tc = (tid & 3) * 16;
  short8 o0, o1;
#pragma unroll
  for (int j = 0; j < 8; ++j) { o0[j] = lt[tc + j][d]; o1[j] = lt[tc + 8 + j][d]; }
  short* dp = dst + ((size_t)nh * 64 + d) * Tpad + c0 + tc;
  *(short8*)(dp) = o0;
  *(short8*)(dp + 8) = o1;
}

// ---------------- prepass: masks padded + pre-scaled by log2(e) -------------
__global__ __launch_bounds__(256) void maskk_kernel(
    const float* __restrict__ am, const float* __restrict__ sm,
    const float* __restrict__ gm,
    float* __restrict__ am2, float* __restrict__ sm2, float* __restrict__ gm2) {
  int i = blockIdx.x * 256 + threadIdx.x;
  if (i < 2 * 4352) {
    int n = i / 4352, r = i % 4352, s = r - 128;
    am2[i] = (s >= 0 && s < 4096) ? am[n * 4096 + s] * LOG2E : MNEG;
  } else if (i < 2 * 4352 + 2 * 1344) {
    int j = i - 2 * 4352;
    int n = j / 1344, r = j % 1344, s = r - 160;
    sm2[j] = (s >= 0 && s < 1024) ? sm[n * 1024 + s] * LOG2E : MNEG;
  } else if (i < 2 * 4352 + 2 * 1344 + 2 * 64) {
    int j = i - 2 * 4352 - 2 * 1344;
    gm2[j] = gm[j] * LOG2E;
  }
}

// ---------------- main attention kernel (8 waves / 512 threads) -------------
// One workgroup per (n,h,block); wave w owns queries [w*16, w*16+16).
// 11 tiles of 64 keys: tile0 global | 1-4 sparse | 5-10 local.
// K rows in LDS are key-interleaved: row r <- source key 4*(r&15)+(r>>4), so
// each lane's 4 P values (kt=0..3, col c) are consecutive keys 4c..4c+3.
// NOTE: (512,4) -> 128-VGPR cap. (512,6) caused catastrophic spill (r4).
__global__ __launch_bounds__(512, 4) void lsg_attn3(
    const short* __restrict__ KL, const short* __restrict__ VTL,
    const short* __restrict__ KS, const short* __restrict__ VTS,
    const short* __restrict__ KG, const short* __restrict__ VTG,
    const float* __restrict__ AM2, const float* __restrict__ SM2,
    const float* __restrict__ GM2,
    const float* __restrict__ q_, float* __restrict__ out) {
  constexpr int TPL = 4352, TPS = 1344;
  __shared__ __align__(16) char smem[53248];
  short (*k_lds)[64][72] = (short(*)[64][72])(smem);           // 18432 B
  short (*v_lds)[64][72] = (short(*)[64][72])(smem + 18432);   // 18432 B
  short* p_all = (short*)(smem + 36864);                        // [8][16][64]

  int bid = blockIdx.x;
  bid = (bid & 7) * 96 + (bid >> 3);        // XCD-contiguous logical ids
  const int b = bid & 31, nh = bid >> 5, n_ = nh / 12;
  const int tid = threadIdx.x;
  const int wid = tid >> 6, lane = tid & 63;
  const int c = lane & 15, g = lane >> 4;
  const int r = tid >> 3, ch = tid & 7;     // staging: 64 rows x 8 chunks
  const int skey = 4 * (r & 15) + (r >> 4); // interleaved K source key for row r
  char* pbase = (char*)(p_all + wid * (16 * 64));

  // ---- Q fragments: wave's 16 rows ----
  const float* qb = q_ + ((size_t)nh * 4096 + (size_t)b * 128 + wid * 16) * 64;
  short8 qa[2];
#pragma unroll
  for (int kc = 0; kc < 2; ++kc) {
    const float* qp = qb + (size_t)c * 64 + kc * 32 + g * 8;
    float4 f0 = *(const float4*)(qp);
    float4 f1 = *(const float4*)(qp + 4);
    short8 tq;
    tq[0] = f2bf(f0.x); tq[1] = f2bf(f0.y); tq[2] = f2bf(f0.z); tq[3] = f2bf(f0.w);
    tq[4] = f2bf(f1.x); tq[5] = f2bf(f1.y); tq[6] = f2bf(f1.z); tq[7] = f2bf(f1.w);
    qa[kc] = tq;
  }

  f32x4 acc[4];
  float mrun[4], lrun[4];
#pragma unroll
  for (int dd = 0; dd < 4; ++dd) acc[dd] = f32x4{0.f, 0.f, 0.f, 0.f};
#pragma unroll
  for (int j = 0; j < 4; ++j) { mrun[j] = MINIT; lrun[j] = 0.f; }

  auto src_for = [&](int t, const short*& kp, const short*& vp,
                     const float*& mp, int& stride) {
    if (t == 0) {
      kp = KG + (size_t)nh * (64 * 64);
      vp = VTG + (size_t)nh * (64 * 64);
      mp = GM2 + n_ * 64;
      stride = 64;
    } else if (t <= 4) {
      int r0 = b * 32 + (t - 1) * 64 + (t >= 3 ? 96 : 0);
      kp = KS + ((size_t)nh * TPS + r0) * 64;
      vp = VTS + (size_t)nh * (64 * TPS) + r0;
      mp = SM2 + n_ * TPS + r0;
      stride = TPS;
    } else {
      int r0 = b * 128 + (t - 5) * 64;
      kp = KL + ((size_t)nh * TPL + r0) * 64;
      vp = VTL + (size_t)nh * (64 * TPL) + r0;
      mp = AM2 + n_ * TPL + r0;
      stride = TPL;
    }
  };

  short8 kr, vr;
  float m_cur[4], m_nxt[4];

  // ---- prologue: tile0 -> buf0, load tile1 regs, tile0 masks ----
  {
    const short* kp; const short* vp; const float* mp; int st;
    src_for(0, kp, vp, mp, st);
    kr = *(const short8*)(kp + skey * 64 + ch * 8);
    vr = *(const short8*)(vp + (size_t)r * st + ch * 8);
#pragma unroll
    for (int i = 0; i < 4; ++i) m_cur[i] = mp[4 * c + i];
    *(short8*)(&k_lds[0][r][ch * 8]) = kr;
    *(short8*)(&v_lds[0][r][ch * 8]) = vr;
    src_for(1, kp, vp, mp, st);
    kr = *(const short8*)(kp + skey * 64 + ch * 8);
    vr = *(const short8*)(vp + (size_t)r * st + ch * 8);
  }

  for (int t = 0; t < 11; ++t) {
    __syncthreads();
    const int cur = t & 1, nxt = cur ^ 1;
    if (t < 10) {   // write staged tile t+1
      *(short8*)(&k_lds[nxt][r][ch * 8]) = kr;
      *(short8*)(&v_lds[nxt][r][ch * 8]) = vr;
    }
    if (t < 9) {    // prefetch tile t+2 into regs
      const short* kp; const short* vp; const float* mp; int st;
      src_for(t + 2, kp, vp, mp, st);
      kr = *(const short8*)(kp + skey * 64 + ch * 8);
      vr = *(const short8*)(vp + (size_t)r * st + ch * 8);
    }
    if (t < 10) {   // tile t+1 masks
      const short* kp; const short* vp; const float* mp; int st;
      src_for(t + 1, kp, vp, mp, st);
#pragma unroll
      for (int i = 0; i < 4; ++i) m_nxt[i] = mp[4 * c + i];
    }

    // ---- QK^T: 16q x 64k ----
    short8 bk[4][2];
#pragma unroll
    for (int kt = 0; kt < 4; ++kt)
#pragma unroll
      for (int kc = 0; kc < 2; ++kc)
        bk[kt][kc] = *(const short8*)(&k_lds[cur][kt * 16 + c][kc * 32 + g * 8]);
    f32x4 s4[4];
    __builtin_amdgcn_s_setprio(1);
#pragma unroll
    for (int kt = 0; kt < 4; ++kt) {
      f32x4 z = f32x4{0.f, 0.f, 0.f, 0.f};
      z = __builtin_amdgcn_mfma_f32_16x16x32_bf16(qa[0], bk[kt][0], z, 0, 0, 0);
      z = __builtin_amdgcn_mfma_f32_16x16x32_bf16(qa[1], bk[kt][1], z, 0, 0, 0);
      s4[kt] = z;
    }
    __builtin_amdgcn_s_setprio(0);
    // scale + mask, log2 domain
#pragma unroll
    for (int kt = 0; kt < 4; ++kt)
#pragma unroll
      for (int j = 0; j < 4; ++j)
        s4[kt][j] = fmaf(s4[kt][j], SCL2, m_cur[kt]);

    // ---- softmax pass 1 (optimistic, defer-max) ----
    float rs[4];
    float worst = 0.f;
#pragma unroll
    for (int j = 0; j < 4; ++j) {
      float mo = mrun[j];
      float p0 = exp2g(s4[0][j] - mo);
      float p1 = exp2g(s4[1][j] - mo);
      float p2 = exp2g(s4[2][j] - mo);
      float p3 = exp2g(s4[3][j] - mo);
      rs[j] = (p0 + p1) + (p2 + p3);
      worst = fmaxf(worst, rs[j]);
      unsigned w0 = cvt_pk_bf16(p0, p1);
      unsigned w1 = cvt_pk_bf16(p2, p3);
      int row = 4 * g + j;
      unsigned bo = ((unsigned)row << 7) + ((unsigned)c << 3);
      bo ^= (unsigned)((row & 7) << 4);
      uint2 u; u.x = w0; u.y = w1;
      *(uint2*)(pbase + bo) = u;
    }

    if (__any(worst > 4096.f)) {   // tile 0 + rare genuine max growth
#pragma unroll
      for (int j = 0; j < 4; ++j) {
        float v0 = s4[0][j], v1 = s4[1][j];
        float v2 = s4[2][j], v3 = s4[3][j];
        float tv = fmaxf(fmaxf(v0, v1), fmaxf(v2, v3));
        tv = fmaxf(tv, __shfl_xor(tv, 1));
        tv = fmaxf(tv, __shfl_xor(tv, 2));
        tv = fmaxf(tv, __shfl_xor(tv, 4));
        tv = fmaxf(tv, __shfl_xor(tv, 8));
        float mo = mrun[j];
        float mn = fmaxf(mo, tv);
        float sc = exp2g(mo - mn);
#pragma unroll
        for (int dd = 0; dd < 4; ++dd) acc[dd][j] *= sc;
        float p0 = exp2g(v0 - mn), p1 = exp2g(v1 - mn);
        float p2 = exp2g(v2 - mn), p3 = exp2g(v3 - mn);
        lrun[j] = lrun[j] * sc + ((p0 + p1) + (p2 + p3));
        mrun[j] = mn;
        unsigned w0 = cvt_pk_bf16(p0, p1);
        unsigned w1 = cvt_pk_bf16(p2, p3);
        int row = 4 * g + j;
        unsigned bo = ((unsigned)row << 7) + ((unsigned)c << 3);
        bo ^= (unsigned)((row & 7) << 4);
        uint2 u; u.x = w0; u.y = w1;
        *(uint2*)(pbase + bo) = u;
      }
    } else {
#pragma unroll
      for (int j = 0; j < 4; ++j) lrun[j] += rs[j];
    }

    // ---- PV: acc += P(16x64) * V(64x64) ----
#pragma unroll
    for (int kk = 0; kk < 2; ++kk) {
      unsigned bo = ((unsigned)c << 7) + (unsigned)(kk * 64 + g * 16);
      bo ^= (unsigned)((c & 7) << 4);
      short8 pa = *(const short8*)(pbase + bo);
      __builtin_amdgcn_s_setprio(1);
#pragma unroll
      for (int dd = 0; dd < 4; ++dd) {
        short8 bv = *(const short8*)(&v_lds[cur][dd * 16 + c][kk * 32 + g * 8]);
        acc[dd] = __builtin_amdgcn_mfma_f32_16x16x32_bf16(pa, bv, acc[dd], 0, 0, 0);
      }
      __builtin_amdgcn_s_setprio(0);
    }
#pragma unroll
    for (int i = 0; i < 4; ++i) m_cur[i] = m_nxt[i];
  }

  // ---- epilogue: reduce l, normalize, coalesce via LDS, dwordx4 stores ----
  float inv[4];
#pragma unroll
  for (int j = 0; j < 4; ++j) {
    float l = lrun[j];
    l += __shfl_xor(l, 1);
    l += __shfl_xor(l, 2);
    l += __shfl_xor(l, 4);
    l += __shfl_xor(l, 8);
    inv[j] = 1.f / l;
  }
  __syncthreads();   // all tiles done; K/V LDS is dead -> reuse as fp32 staging
  float* fst = (float*)smem + wid * (16 * 68);   // per-wave [16][68] fp32
#pragma unroll
  for (int j = 0; j < 4; ++j)
#pragma unroll
    for (int dd = 0; dd < 4; ++dd)
      fst[(4 * g + j) * 68 + dd * 16 + c] = acc[dd][j] * inv[j];
  // same-wave readback (lockstep; compiler inserts lgkmcnt)
  int rr = lane >> 2, cc = lane & 3;
  const float* fs = (float*)smem + wid * (16 * 68) + rr * 68 + cc * 16;
  float* op = out + ((size_t)nh * 4096 + (size_t)b * 128 + wid * 16 + rr) * 64 + cc * 16;
#pragma unroll
  for (int i = 0; i < 4; ++i)
    *(float4*)(op + i * 4) = *(const float4*)(fs + i * 4);
}

// ---------------- fallback (round-1 kernel, used if ws too small) -----------
__global__ __launch_bounds__(256) void lsg_attn_fb(
    const float* __restrict__ q_,  const float* __restrict__ k_,
    const float* __restrict__ v_,  const float* __restrict__ amask,
    const float* __restrict__ sk,  const float* __restrict__ sv,
    const float* __restrict__ smk, const float* __restrict__ gk,
    const float* __restrict__ gv,  const float* __restrict__ gmk,
    float* __restrict__ out) {
  constexpr int T = 4096, D = 64, TS = 1024;
  constexpr float NEGF = -3.402823466e38f;
  __shared__ __align__(16) short k_lds[32][72];
  __shared__ __align__(16) short v_lds[64][40];
  __shared__ __align__(16) short p_lds[4][32][40];
  __shared__ float m_lds[32];
  const int bid = blockIdx.x;
  const int b = bid & 31, nh = bid >> 5, n_ = nh / 12;
  const int tid = threadIdx.x, wid = tid >> 6, lane = tid & 63;
  const int c = lane & 15, g = lane >> 4;
  const float* qb = q_ + ((size_t)nh * T + (size_t)b * 128) * D;
  const float* kb = k_ + (size_t)nh * T * D;
  const float* vb = v_ + (size_t)nh * T * D;
  const float* skb = sk + (size_t)nh * TS * D;
  const float* svb = sv + (size_t)nh * TS * D;
  const float* gkb = gk + (size_t)nh * 64 * D;
  const float* gvb = gv + (size_t)nh * 64 * D;
  const float* am = amask + (size_t)n_ * T;
  const float* sm = smk + (size_t)n_ * TS;
  const float* gm = gmk + (size_t)n_ * 64;
  short8 qa[2][2];
#pragma unroll
  for (int mt = 0; mt < 2; ++mt)
#pragma unroll
    for (int kc = 0; kc < 2; ++kc) {
      const float* qp = qb + (size_t)(wid * 32 + mt * 16 + c) * D + kc * 32 + g * 8;
      short8 t;
#pragma unroll
      for (int j = 0; j < 8; ++j) t[j] = f2bf(qp[j]);
      qa[mt][kc] = t;
    }
  f32x4 acc[2][4];
#pragma unroll
  for (int mt = 0; mt < 2; ++mt)
#pragma unroll
    for (int dd = 0; dd < 4; ++dd) acc[mt][dd] = f32x4{0.f, 0.f, 0.f, 0.f};
  float mrun[2][4], lrun[2][4];
#pragma unroll
  for (int mt = 0; mt < 2; ++mt)
#pragma unroll
    for (int j = 0; j < 4; ++j) { mrun[mt][j] = NEGF; lrun[mt][j] = 0.f; }
  const int key_local = tid >> 3;
  const int seg = tid & 7;
  const int d0 = seg * 8;
  for (int tile = 0; tile < 22; ++tile) {
    __syncthreads();
    {
      const int kk = tile * 32 + key_local;
      const float* ksrc; const float* vsrc; float mval; bool valid;
      if (kk < 64) {
        ksrc = gkb + kk * D; vsrc = gvb + kk * D; mval = gm[kk]; valid = true;
      } else if (kk < 320) {
        int s = b * 32 - 160 + (kk - 64) + ((kk >= 192) ? 96 : 0);
        valid = (s >= 0) && (s < TS);
        int sc2 = valid ? s : 0;
        ksrc = skb + sc2 * D; vsrc = svb + sc2 * D;
        mval = valid ? sm[sc2] : NEGF;
      } else {
        int tt = b * 128 - 128 + (kk - 320);
        valid = (tt >= 0) && (tt < T);
        int tc = valid ? tt : 0;
        ksrc = kb + tc * D; vsrc = vb + tc * D;
        mval = valid ? am[tc] : NEGF;
      }
      short8 k8; short v8[8];
      if (valid) {
#pragma unroll
        for (int j = 0; j < 8; ++j) { k8[j] = f2bf(ksrc[d0 + j]); v8[j] = f2bf(vsrc[d0 + j]); }
      } else {
#pragma unroll
        for (int j = 0; j < 8; ++j) { k8[j] = 0; v8[j] = 0; }
      }
      *(short8*)(&k_lds[key_local][d0]) = k8;
#pragma unroll
      for (int j = 0; j < 8; ++j) v_lds[d0 + j][key_local] = v8[j];
      if (seg == 0) m_lds[key_local] = mval;
    }
    __syncthreads();
    short8 bk[2][2];
#pragma unroll
    for (int kt = 0; kt < 2; ++kt)
#pragma unroll
      for (int kc = 0; kc < 2; ++kc)
        bk[kt][kc] = *(const short8*)(&k_lds[kt * 16 + c][kc * 32 + g * 8]);
    f32x4 s_[2][2];
#pragma unroll
    for (int mt = 0; mt < 2; ++mt)
#pragma unroll
      for (int kt = 0; kt < 2; ++kt) {
        f32x4 z = f32x4{0.f, 0.f, 0.f, 0.f};
        z = __builtin_amdgcn_mfma_f32_16x16x32_bf16(qa[mt][0], bk[kt][0], z, 0, 0, 0);
        z = __builtin_amdgcn_mfma_f32_16x16x32_bf16(qa[mt][1], bk[kt][1], z, 0, 0, 0);
        s_[mt][kt] = z;
      }
    const float msk0 = m_lds[c];
    const float msk1 = m_lds[16 + c];
#pragma unroll
    for (int mt = 0; mt < 2; ++mt) {
#pragma unroll
      for (int j = 0; j < 4; ++j) {
        float s0 = s_[mt][0][j] * 0.125f + msk0;
        float s1 = s_[mt][1][j] * 0.125f + msk1;
        float tv = fmaxf(s0, s1);
        tv = fmaxf(tv, __shfl_xor(tv, 1));
        tv = fmaxf(tv, __shfl_xor(tv, 2));
        tv = fmaxf(tv, __shfl_xor(tv, 4));
        tv = fmaxf(tv, __shfl_xor(tv, 8));
        float mold = mrun[mt][j];
        float mnew = fmaxf(mold, tv);
        float scale = __expf(mold - mnew);
        mrun[mt][j] = mnew;
        float p0 = __expf(s0 - mnew);
        float p1 = __expf(s1 - mnew);
        lrun[mt][j] = lrun[mt][j] * scale + p0 + p1;
#pragma unroll
        for (int dd = 0; dd < 4; ++dd) acc[mt][dd][j] *= scale;
        p_lds[wid][mt * 16 + g * 4 + j][c] = f2bf(p0);
        p_lds[wid][mt * 16 + g * 4 + j][16 + c] = f2bf(p1);
      }
    }
    __syncthreads();
#pragma unroll
    for (int mt = 0; mt < 2; ++mt) {
      short8 pa = *(const short8*)(&p_lds[wid][mt * 16 + c][g * 8]);
#pragma unroll
      for (int dd = 0; dd < 4; ++dd) {
        short8 bv = *(const short8*)(&v_lds[dd * 16 + c][g * 8]);
        acc[mt][dd] = __builtin_amdgcn_mfma_f32_16x16x32_bf16(pa, bv, acc[mt][dd], 0, 0, 0);
      }
    }
  }
  float* ob = out + ((size_t)nh * T + (size_t)b * 128 + (size_t)wid * 32) * D;
#pragma unroll
  for (int mt = 0; mt < 2; ++mt)
#pragma unroll
    for (int j = 0; j < 4; ++j) {
      float l = lrun[mt][j];
      l += __shfl_xor(l, 1);
      l += __shfl_xor(l, 2);
      l += __shfl_xor(l, 4);
      l += __shfl_xor(l, 8);
      float inv = 1.f / l;
      int row = mt * 16 + g * 4 + j;
#pragma unroll
      for (int dd = 0; dd < 4; ++dd)
        ob[(size_t)row * D + dd * 16 + c] = acc[mt][dd][j] * inv;
    }
}

extern "C" void kernel_launch(void* const* d_in, const int* in_sizes, int n_in,
                              void* d_out, int out_size, void* d_ws, size_t ws_size,
                              hipStream_t stream) {
  const float* q  = (const float*)d_in[0];
  const float* k  = (const float*)d_in[1];
  const float* v  = (const float*)d_in[2];
  const float* am = (const float*)d_in[3];
  const float* sk = (const float*)d_in[4];
  const float* sv = (const float*)d_in[5];
  const float* sm = (const float*)d_in[6];
  const float* gk = (const float*)d_in[7];
  const float* gv = (const float*)d_in[8];
  const float* gm = (const float*)d_in[9];
  float* out = (float*)d_out;

  size_t off = 0;
  char* base = (char*)d_ws;
  auto alloc = [&](size_t bytes) { void* p = base + off; off += bytes; return p; };
  short* KL  = (short*)alloc(13369344);  // [24][4352][64] bf16
  short* VTL = (short*)alloc(13369344);  // [24][64][4352]
  short* KS  = (short*)alloc(4128768);   // [24][1344][64]
  short* VTS = (short*)alloc(4128768);   // [24][64][1344]
  short* KG  = (short*)alloc(196608);    // [24][64][64]
  short* VTG = (short*)alloc(196608);    // [24][64][64]
  float* AM2 = (float*)alloc(34816);     // [2][4352]
  float* SM2 = (float*)alloc(10752);     // [2][1344]
  float* GM2 = (float*)alloc(512);       // [2][64]

  if (off <= ws_size) {
    hipLaunchKernelGGL(convk_kernel, dim3(3264), dim3(256), 0, stream, k,  KL, 4096, 128, 24 * 4352 * 8);
    hipLaunchKernelGGL(convk_kernel, dim3(1008), dim3(256), 0, stream, sk, KS, 1024, 160, 24 * 1344 * 8);
    hipLaunchKernelGGL(convk_kernel, dim3(48),   dim3(256), 0, stream, gk, KG, 64,   0,   24 * 64 * 8);
    hipLaunchKernelGGL(transv_kernel, dim3(24 * 68), dim3(256), 0, stream, v,  VTL, 4096, 128, 68);
    hipLaunchKernelGGL(transv_kernel, dim3(24 * 21), dim3(256), 0, stream, sv, VTS, 1024, 160, 21);
    hipLaunchKernelGGL(transv_kernel, dim3(24),      dim3(256), 0, stream, gv, VTG, 64,   0,   1);
    hipLaunchKernelGGL(maskk_kernel, dim3(45), dim3(256), 0, stream, am, sm, gm, AM2, SM2, GM2);
    hipLaunchKernelGGL(lsg_attn3, dim3(768), dim3(512), 0, stream,
                       KL, VTL, KS, VTS, KG, VTG, AM2, SM2, GM2, q, out);
  } else {
    hipLaunchKernelGGL(lsg_attn_fb, dim3(768), dim3(256), 0, stream,
                       q, k, v, am, sk, sv, sm, gk, gv, gm, out);
  }
}

// Round 7
// 59.524 us; speedup vs baseline: 3.8852x; 1.2056x over previous
//
#include <hip/hip_runtime.h>
#include <hip/hip_bf16.h>

typedef __attribute__((ext_vector_type(8))) short short8;
typedef __attribute__((ext_vector_type(4))) float f32x4;

#define LOG2E 1.44269504f
#define SCL2  0.18033688f   // 0.125 * log2(e)
#define MNEG  -3.0e38f
#define MINIT -1.0e30f

__device__ __forceinline__ short f2bf(float f) {
  union { float f; unsigned u; } x; x.f = f;
  return (short)((x.u + 0x7FFFu + ((x.u >> 16) & 1u)) >> 16);  // RNE
}
__device__ __forceinline__ float exp2g(float x) {
  float r; asm("v_exp_f32 %0, %1" : "=v"(r) : "v"(x)); return r;
}
__device__ __forceinline__ unsigned cvt_pk_bf16(float lo, float hi) {
  unsigned r;
  asm("v_cvt_pk_bf16_f32 %0, %1, %2" : "=v"(r) : "v"(lo), "v"(hi));
  return r;
}

// ---------------- fused prepass 1: fp32->bf16 K (3 tensors) + masks ---------
__device__ __forceinline__ void conv_one(
    const float* __restrict__ src, short* __restrict__ dst,
    int Tin, int pad, int cid) {
  int Tpad = Tin + 2 * pad;
  int row = cid >> 3;
  int d0 = (cid & 7) * 8;
  int tok = row % Tpad;
  int nh = row / Tpad;
  int st = tok - pad;
  short8 o;
  if (st >= 0 && st < Tin) {
    const float4* sp = (const float4*)(src + ((size_t)nh * Tin + st) * 64 + d0);
    float4 f0 = sp[0], f1 = sp[1];
    o[0] = f2bf(f0.x); o[1] = f2bf(f0.y); o[2] = f2bf(f0.z); o[3] = f2bf(f0.w);
    o[4] = f2bf(f1.x); o[5] = f2bf(f1.y); o[6] = f2bf(f1.z); o[7] = f2bf(f1.w);
  } else {
#pragma unroll
    for (int j = 0; j < 8; ++j) o[j] = 0;
  }
  *(short8*)(dst + (size_t)row * 64 + d0) = o;
}

__global__ __launch_bounds__(256) void conv_fused(
    const float* __restrict__ K, const float* __restrict__ SK,
    const float* __restrict__ GK,
    short* __restrict__ KL, short* __restrict__ KS, short* __restrict__ KG,
    const float* __restrict__ am, const float* __restrict__ sm,
    const float* __restrict__ gm,
    float* __restrict__ AM2, float* __restrict__ SM2, float* __restrict__ GM2) {
  int cid = blockIdx.x * 256 + threadIdx.x;
  const int nL = 24 * 4352 * 8;          // 835584
  const int nS = nL + 24 * 1344 * 8;     // 1093632
  const int nG = nS + 24 * 64 * 8;       // 1105920
  if (cid < nL) { conv_one(K, KL, 4096, 128, cid); return; }
  if (cid < nS) { conv_one(SK, KS, 1024, 160, cid - nL); return; }
  if (cid < nG) { conv_one(GK, KG, 64, 0, cid - nS); return; }
  int i = cid - nG;   // mask work: 11520 elements
  if (i < 2 * 4352) {
    int n = i / 4352, rr = i % 4352, s = rr - 128;
    AM2[i] = (s >= 0 && s < 4096) ? am[n * 4096 + s] * LOG2E : MNEG;
  } else if (i < 2 * 4352 + 2 * 1344) {
    int j = i - 2 * 4352;
    int n = j / 1344, rr = j % 1344, s = rr - 160;
    SM2[j] = (s >= 0 && s < 1024) ? sm[n * 1024 + s] * LOG2E : MNEG;
  } else if (i < 2 * 4352 + 2 * 1344 + 2 * 64) {
    int j = i - 2 * 4352 - 2 * 1344;
    GM2[j] = gm[j] * LOG2E;
  }
}

// ---------------- fused prepass 2: fp32 V -> bf16 V^T (3 tensors) -----------
__device__ __forceinline__ void transv_one(
    const float* __restrict__ src, short* __restrict__ dst,
    int Tin, int pad, int tiles, int bidx, int tid, short (*lt)[72]) {
  int tile = bidx % tiles;
  int nh = bidx / tiles;
  int Tpad = Tin + 2 * pad;
  int c0 = tile * 64;
  int tok = tid >> 2;
  int dc = (tid & 3) * 16;
  int st = c0 + tok - pad;
  if (st >= 0 && st < Tin) {
    const float4* sp = (const float4*)(src + ((size_t)nh * Tin + st) * 64 + dc);
#pragma unroll
    for (int i = 0; i < 4; ++i) {
      float4 f = sp[i];
      lt[tok][dc + i * 4 + 0] = f2bf(f.x);
      lt[tok][dc + i * 4 + 1] = f2bf(f.y);
      lt[tok][dc + i * 4 + 2] = f2bf(f.z);
      lt[tok][dc + i * 4 + 3] = f2bf(f.w);
    }
  } else {
#pragma unroll
    for (int i = 0; i < 16; ++i) lt[tok][dc + i] = 0;
  }
  __syncthreads();
  int d = tid >> 2;
  int tc = (tid & 3) * 16;
  short8 o0, o1;
#pragma unroll
  for (int j = 0; j < 8; ++j) { o0[j] = lt[tc + j][d]; o1[j] = lt[tc + 8 + j][d]; }
  short* dp = dst + ((size_t)nh * 64 + d) * Tpad + c0 + tc;
  *(short8*)(dp) = o0;
  *(short8*)(dp + 8) = o1;
}

__global__ __launch_bounds__(256) void transv_fused(
    const float* __restrict__ V, const float* __restrict__ SV,
    const float* __restrict__ GV,
    short* __restrict__ VTL, short* __restrict__ VTS, short* __restrict__ VTG) {
  __shared__ short lt[64][72];
  int bidx = blockIdx.x;
  int tid = threadIdx.x;
  if (bidx < 24 * 68) { transv_one(V, VTL, 4096, 128, 68, bidx, tid, lt); return; }
  bidx -= 24 * 68;
  if (bidx < 24 * 21) { transv_one(SV, VTS, 1024, 160, 21, bidx, tid, lt); return; }
  bidx -= 24 * 21;
  transv_one(GV, VTG, 64, 0, 1, bidx, tid, lt);
}

// ---------------- main attention kernel (8 waves, swizzled LDS) -------------
// One workgroup per (n,h,block); wave w owns queries [w*16, w*16+16).
// 11 tiles of 64 keys: tile0 global | 1-4 sparse | 5-10 local.
// K rows in LDS are key-interleaved: row r <- source key 4*(r&15)+(r>>4).
// K/V LDS: [64 rows][128 B], byte = row*128 + (col16 ^ ((row&7)<<4)) both
// on write and read -> staging writes conflict-free, reads 2-way (free).
// Tile-loop barrier: lgkmcnt(0)+s_barrier only (no vmcnt drain; global
// prefetches land in registers, no cross-wave LDS hazard).
__global__ __launch_bounds__(512, 4) void lsg_attn5(
    const short* __restrict__ KL, const short* __restrict__ VTL,
    const short* __restrict__ KS, const short* __restrict__ VTS,
    const short* __restrict__ KG, const short* __restrict__ VTG,
    const float* __restrict__ AM2, const float* __restrict__ SM2,
    const float* __restrict__ GM2,
    const float* __restrict__ q_, float* __restrict__ out) {
  constexpr int TPL = 4352, TPS = 1344;
  __shared__ __align__(16) char smem[49152];   // K dbuf 16K | V dbuf 16K | P 16K

  int bid = blockIdx.x;
  bid = (bid & 7) * 96 + (bid >> 3);        // XCD-contiguous logical ids
  const int b = bid & 31, nh = bid >> 5, n_ = nh / 12;
  const int tid = threadIdx.x;
  const int wid = tid >> 6, lane = tid & 63;
  const int c = lane & 15, g = lane >> 4;
  const int r = tid >> 3, ch = tid & 7;     // staging: 64 rows x 8 chunks(16B)
  const int skey = 4 * (r & 15) + (r >> 4); // interleaved K source key for row r
  char* pbase = smem + 32768 + wid * 2048;  // per-wave P [16][64] bf16
  const unsigned stg = ((unsigned)r << 7) + ((unsigned)(ch * 16) ^ ((unsigned)(r & 7) << 4));

  // ---- Q fragments: wave's 16 rows ----
  const float* qb = q_ + ((size_t)nh * 4096 + (size_t)b * 128 + wid * 16) * 64;
  short8 qa[2];
#pragma unroll
  for (int kc = 0; kc < 2; ++kc) {
    const float* qp = qb + (size_t)c * 64 + kc * 32 + g * 8;
    float4 f0 = *(const float4*)(qp);
    float4 f1 = *(const float4*)(qp + 4);
    short8 tq;
    tq[0] = f2bf(f0.x); tq[1] = f2bf(f0.y); tq[2] = f2bf(f0.z); tq[3] = f2bf(f0.w);
    tq[4] = f2bf(f1.x); tq[5] = f2bf(f1.y); tq[6] = f2bf(f1.z); tq[7] = f2bf(f1.w);
    qa[kc] = tq;
  }

  f32x4 acc[4];
  float mrun[4], lrun[4];
#pragma unroll
  for (int dd = 0; dd < 4; ++dd) acc[dd] = f32x4{0.f, 0.f, 0.f, 0.f};
#pragma unroll
  for (int j = 0; j < 4; ++j) { mrun[j] = MINIT; lrun[j] = 0.f; }

  auto src_for = [&](int t, const short*& kp, const short*& vp,
                     const float*& mp, int& stride) {
    if (t == 0) {
      kp = KG + (size_t)nh * (64 * 64);
      vp = VTG + (size_t)nh * (64 * 64);
      mp = GM2 + n_ * 64;
      stride = 64;
    } else if (t <= 4) {
      int r0 = b * 32 + (t - 1) * 64 + (t >= 3 ? 96 : 0);
      kp = KS + ((size_t)nh * TPS + r0) * 64;
      vp = VTS + (size_t)nh * (64 * TPS) + r0;
      mp = SM2 + n_ * TPS + r0;
      stride = TPS;
    } else {
      int r0 = b * 128 + (t - 5) * 64;
      kp = KL + ((size_t)nh * TPL + r0) * 64;
      vp = VTL + (size_t)nh * (64 * TPL) + r0;
      mp = AM2 + n_ * TPL + r0;
      stride = TPL;
    }
  };

  short8 kr, vr;
  float m_cur[4], m_nxt[4];

  // ---- prologue: tile0 -> buf0, load tile1 regs, tile0 masks ----
  {
    const short* kp; const short* vp; const float* mp; int st;
    src_for(0, kp, vp, mp, st);
    kr = *(const short8*)(kp + skey * 64 + ch * 8);
    vr = *(const short8*)(vp + (size_t)r * st + ch * 8);
#pragma unroll
    for (int i = 0; i < 4; ++i) m_cur[i] = mp[4 * c + i];
    *(short8*)(smem + stg) = kr;
    *(short8*)(smem + 16384 + stg) = vr;
    src_for(1, kp, vp, mp, st);
    kr = *(const short8*)(kp + skey * 64 + ch * 8);
    vr = *(const short8*)(vp + (size_t)r * st + ch * 8);
  }

  for (int t = 0; t < 11; ++t) {
    // own LDS ops drained, then workgroup barrier; vmcnt NOT drained
    asm volatile("s_waitcnt lgkmcnt(0)\n\ts_barrier" ::: "memory");
    const int cur = t & 1, nxt = cur ^ 1;
    char* kbuf = smem + cur * 8192;
    char* vbuf = smem + 16384 + cur * 8192;

    // ---- 1. QK^T K-fragment reads first (longest latency to MFMA) ----
    short8 bk[4][2];
#pragma unroll
    for (int kt = 0; kt < 4; ++kt)
#pragma unroll
      for (int kc = 0; kc < 2; ++kc) {
        unsigned off = ((unsigned)(kt * 16 + c) << 7) +
                       ((unsigned)(kc * 64 + g * 16) ^ ((unsigned)(c & 7) << 4));
        bk[kt][kc] = *(const short8*)(kbuf + off);
      }

    // ---- 2. write staged tile t+1 ----
    if (t < 10) {
      *(short8*)(smem + nxt * 8192 + stg) = kr;
      *(short8*)(smem + 16384 + nxt * 8192 + stg) = vr;
    }
    // ---- 3. prefetch tile t+2 into regs ----
    if (t < 9) {
      const short* kp; const short* vp; const float* mp; int st;
      src_for(t + 2, kp, vp, mp, st);
      kr = *(const short8*)(kp + skey * 64 + ch * 8);
      vr = *(const short8*)(vp + (size_t)r * st + ch * 8);
    }
    if (t < 10) {   // tile t+1 masks
      const short* kp; const short* vp; const float* mp; int st;
      src_for(t + 1, kp, vp, mp, st);
#pragma unroll
      for (int i = 0; i < 4; ++i) m_nxt[i] = mp[4 * c + i];
    }

    // ---- QK^T: 16q x 64k ----
    f32x4 s4[4];
    __builtin_amdgcn_s_setprio(1);
#pragma unroll
    for (int kt = 0; kt < 4; ++kt) {
      f32x4 z = f32x4{0.f, 0.f, 0.f, 0.f};
      z = __builtin_amdgcn_mfma_f32_16x16x32_bf16(qa[0], bk[kt][0], z, 0, 0, 0);
      z = __builtin_amdgcn_mfma_f32_16x16x32_bf16(qa[1], bk[kt][1], z, 0, 0, 0);
      s4[kt] = z;
    }
    __builtin_amdgcn_s_setprio(0);
#pragma unroll
    for (int kt = 0; kt < 4; ++kt)
#pragma unroll
      for (int j = 0; j < 4; ++j)
        s4[kt][j] = fmaf(s4[kt][j], SCL2, m_cur[kt]);

    // ---- softmax pass 1 (optimistic, defer-max) ----
    float rs[4];
    float worst = 0.f;
#pragma unroll
    for (int j = 0; j < 4; ++j) {
      float mo = mrun[j];
      float p0 = exp2g(s4[0][j] - mo);
      float p1 = exp2g(s4[1][j] - mo);
      float p2 = exp2g(s4[2][j] - mo);
      float p3 = exp2g(s4[3][j] - mo);
      rs[j] = (p0 + p1) + (p2 + p3);
      worst = fmaxf(worst, rs[j]);
      unsigned w0 = cvt_pk_bf16(p0, p1);
      unsigned w1 = cvt_pk_bf16(p2, p3);
      int row = 4 * g + j;
      unsigned bo = ((unsigned)row << 7) + ((unsigned)c << 3);
      bo ^= (unsigned)((row & 7) << 4);
      uint2 u; u.x = w0; u.y = w1;
      *(uint2*)(pbase + bo) = u;
    }

    if (__any(worst > 4096.f)) {   // tile 0 + rare genuine max growth
#pragma unroll
      for (int j = 0; j < 4; ++j) {
        float v0 = s4[0][j], v1 = s4[1][j];
        float v2 = s4[2][j], v3 = s4[3][j];
        float tv = fmaxf(fmaxf(v0, v1), fmaxf(v2, v3));
        tv = fmaxf(tv, __shfl_xor(tv, 1));
        tv = fmaxf(tv, __shfl_xor(tv, 2));
        tv = fmaxf(tv, __shfl_xor(tv, 4));
        tv = fmaxf(tv, __shfl_xor(tv, 8));
        float mo = mrun[j];
        float mn = fmaxf(mo, tv);
        float sc = exp2g(mo - mn);
#pragma unroll
        for (int dd = 0; dd < 4; ++dd) acc[dd][j] *= sc;
        float p0 = exp2g(v0 - mn), p1 = exp2g(v1 - mn);
        float p2 = exp2g(v2 - mn), p3 = exp2g(v3 - mn);
        lrun[j] = lrun[j] * sc + ((p0 + p1) + (p2 + p3));
        mrun[j] = mn;
        unsigned w0 = cvt_pk_bf16(p0, p1);
        unsigned w1 = cvt_pk_bf16(p2, p3);
        int row = 4 * g + j;
        unsigned bo = ((unsigned)row << 7) + ((unsigned)c << 3);
        bo ^= (unsigned)((row & 7) << 4);
        uint2 u; u.x = w0; u.y = w1;
        *(uint2*)(pbase + bo) = u;
      }
    } else {
#pragma unroll
      for (int j = 0; j < 4; ++j) lrun[j] += rs[j];
    }

    // ---- PV: acc += P(16x64) * V(64x64) ----
#pragma unroll
    for (int kk = 0; kk < 2; ++kk) {
      unsigned bo = ((unsigned)c << 7) + (unsigned)(kk * 64 + g * 16);
      bo ^= (unsigned)((c & 7) << 4);
      short8 pa = *(const short8*)(pbase + bo);
      __builtin_amdgcn_s_setprio(1);
#pragma unroll
      for (int dd = 0; dd < 4; ++dd) {
        unsigned voff = ((unsigned)(dd * 16 + c) << 7) +
                        ((unsigned)(kk * 64 + g * 16) ^ ((unsigned)(c & 7) << 4));
        short8 bv = *(const short8*)(vbuf + voff);
        acc[dd] = __builtin_amdgcn_mfma_f32_16x16x32_bf16(pa, bv, acc[dd], 0, 0, 0);
      }
      __builtin_amdgcn_s_setprio(0);
    }
#pragma unroll
    for (int i = 0; i < 4; ++i) m_cur[i] = m_nxt[i];
  }

  // ---- epilogue: reduce l, normalize, coalesce via LDS, dwordx4 stores ----
  float inv[4];
#pragma unroll
  for (int j = 0; j < 4; ++j) {
    float l = lrun[j];
    l += __shfl_xor(l, 1);
    l += __shfl_xor(l, 2);
    l += __shfl_xor(l, 4);
    l += __shfl_xor(l, 8);
    inv[j] = 1.f / l;
  }
  __syncthreads();   // all tiles done; K/V LDS dead -> reuse as fp32 staging
  float* fst = (float*)smem + wid * (16 * 68);   // per-wave [16][68] fp32
#pragma unroll
  for (int j = 0; j < 4; ++j)
#pragma unroll
    for (int dd = 0; dd < 4; ++dd)
      fst[(4 * g + j) * 68 + dd * 16 + c] = acc[dd][j] * inv[j];
  int rr = lane >> 2, cc = lane & 3;
  const float* fs = (float*)smem + wid * (16 * 68) + rr * 68 + cc * 16;
  float* op = out + ((size_t)nh * 4096 + (size_t)b * 128 + wid * 16 + rr) * 64 + cc * 16;
#pragma unroll
  for (int i = 0; i < 4; ++i)
    *(float4*)(op + i * 4) = *(const float4*)(fs + i * 4);
}

// ---------------- fallback (round-1 kernel, used if ws too small) -----------
__global__ __launch_bounds__(256) void lsg_attn_fb(
    const float* __restrict__ q_,  const float* __restrict__ k_,
    const float* __restrict__ v_,  const float* __restrict__ amask,
    const float* __restrict__ sk,  const float* __restrict__ sv,
    const float* __restrict__ smk, const float* __restrict__ gk,
    const float* __restrict__ gv,  const float* __restrict__ gmk,
    float* __restrict__ out) {
  constexpr int T = 4096, D = 64, TS = 1024;
  constexpr float NEGF = -3.402823466e38f;
  __shared__ __align__(16) short k_lds[32][72];
  __shared__ __align__(16) short v_lds[64][40];
  __shared__ __align__(16) short p_lds[4][32][40];
  __shared__ float m_lds[32];
  const int bid = blockIdx.x;
  const int b = bid & 31, nh = bid >> 5, n_ = nh / 12;
  const int tid = threadIdx.x, wid = tid >> 6, lane = tid & 63;
  const int c = lane & 15, g = lane >> 4;
  const float* qb = q_ + ((size_t)nh * T + (size_t)b * 128) * D;
  const float* kb = k_ + (size_t)nh * T * D;
  const float* vb = v_ + (size_t)nh * T * D;
  const float* skb = sk + (size_t)nh * TS * D;
  const float* svb = sv + (size_t)nh * TS * D;
  const float* gkb = gk + (size_t)nh * 64 * D;
  const float* gvb = gv + (size_t)nh * 64 * D;
  const float* am = amask + (size_t)n_ * T;
  const float* sm = smk + (size_t)n_ * TS;
  const float* gm = gmk + (size_t)n_ * 64;
  short8 qa[2][2];
#pragma unroll
  for (int mt = 0; mt < 2; ++mt)
#pragma unroll
    for (int kc = 0; kc < 2; ++kc) {
      const float* qp = qb + (size_t)(wid * 32 + mt * 16 + c) * D + kc * 32 + g * 8;
      short8 t;
#pragma unroll
      for (int j = 0; j < 8; ++j) t[j] = f2bf(qp[j]);
      qa[mt][kc] = t;
    }
  f32x4 acc[2][4];
#pragma unroll
  for (int mt = 0; mt < 2; ++mt)
#pragma unroll
    for (int dd = 0; dd < 4; ++dd) acc[mt][dd] = f32x4{0.f, 0.f, 0.f, 0.f};
  float mrun[2][4], lrun[2][4];
#pragma unroll
  for (int mt = 0; mt < 2; ++mt)
#pragma unroll
    for (int j = 0; j < 4; ++j) { mrun[mt][j] = NEGF; lrun[mt][j] = 0.f; }
  const int key_local = tid >> 3;
  const int seg = tid & 7;
  const int d0 = seg * 8;
  for (int tile = 0; tile < 22; ++tile) {
    __syncthreads();
    {
      const int kk = tile * 32 + key_local;
      const float* ksrc; const float* vsrc; float mval; bool valid;
      if (kk < 64) {
        ksrc = gkb + kk * D; vsrc = gvb + kk * D; mval = gm[kk]; valid = true;
      } else if (kk < 320) {
        int s = b * 32 - 160 + (kk - 64) + ((kk >= 192) ? 96 : 0);
        valid = (s >= 0) && (s < TS);
        int sc2 = valid ? s : 0;
        ksrc = skb + sc2 * D; vsrc = svb + sc2 * D;
        mval = valid ? sm[sc2] : NEGF;
      } else {
        int tt = b * 128 - 128 + (kk - 320);
        valid = (tt >= 0) && (tt < T);
        int tc = valid ? tt : 0;
        ksrc = kb + tc * D; vsrc = vb + tc * D;
        mval = valid ? am[tc] : NEGF;
      }
      short8 k8; short v8[8];
      if (valid) {
#pragma unroll
        for (int j = 0; j < 8; ++j) { k8[j] = f2bf(ksrc[d0 + j]); v8[j] = f2bf(vsrc[d0 + j]); }
      } else {
#pragma unroll
        for (int j = 0; j < 8; ++j) { k8[j] = 0; v8[j] = 0; }
      }
      *(short8*)(&k_lds[key_local][d0]) = k8;
#pragma unroll
      for (int j = 0; j < 8; ++j) v_lds[d0 + j][key_local] = v8[j];
      if (seg == 0) m_lds[key_local] = mval;
    }
    __syncthreads();
    short8 bk[2][2];
#pragma unroll
    for (int kt = 0; kt < 2; ++kt)
#pragma unroll
      for (int kc = 0; kc < 2; ++kc)
        bk[kt][kc] = *(const short8*)(&k_lds[kt * 16 + c][kc * 32 + g * 8]);
    f32x4 s_[2][2];
#pragma unroll
    for (int mt = 0; mt < 2; ++mt)
#pragma unroll
      for (int kt = 0; kt < 2; ++kt) {
        f32x4 z = f32x4{0.f, 0.f, 0.f, 0.f};
        z = __builtin_amdgcn_mfma_f32_16x16x32_bf16(qa[mt][0], bk[kt][0], z, 0, 0, 0);
        z = __builtin_amdgcn_mfma_f32_16x16x32_bf16(qa[mt][1], bk[kt][1], z, 0, 0, 0);
        s_[mt][kt] = z;
      }
    const float msk0 = m_lds[c];
    const float msk1 = m_lds[16 + c];
#pragma unroll
    for (int mt = 0; mt < 2; ++mt) {
#pragma unroll
      for (int j = 0; j < 4; ++j) {
        float s0 = s_[mt][0][j] * 0.125f + msk0;
        float s1 = s_[mt][1][j] * 0.125f + msk1;
        float tv = fmaxf(s0, s1);
        tv = fmaxf(tv, __shfl_xor(tv, 1));
        tv = fmaxf(tv, __shfl_xor(tv, 2));
        tv = fmaxf(tv, __shfl_xor(tv, 4));
        tv = fmaxf(tv, __shfl_xor(tv, 8));
        float mold = mrun[mt][j];
        float mnew = fmaxf(mold, tv);
        float scale = __expf(mold - mnew);
        mrun[mt][j] = mnew;
        float p0 = __expf(s0 - mnew);
        float p1 = __expf(s1 - mnew);
        lrun[mt][j] = lrun[mt][j] * scale + p0 + p1;
#pragma unroll
        for (int dd = 0; dd < 4; ++dd) acc[mt][dd][j] *= scale;
        p_lds[wid][mt * 16 + g * 4 + j][c] = f2bf(p0);
        p_lds[wid][mt * 16 + g * 4 + j][16 + c] = f2bf(p1);
      }
    }
    __syncthreads();
#pragma unroll
    for (int mt = 0; mt < 2; ++mt) {
      short8 pa = *(const short8*)(&p_lds[wid][mt * 16 + c][g * 8]);
#pragma unroll
      for (int dd = 0; dd < 4; ++dd) {
        short8 bv = *(const short8*)(&v_lds[dd * 16 + c][g * 8]);
        acc[mt][dd] = __builtin_amdgcn_mfma_f32_16x16x32_bf16(pa, bv, acc[mt][dd], 0, 0, 0);
      }
    }
  }
  float* ob = out + ((size_t)nh * T + (size_t)b * 128 + (size_t)wid * 32) * D;
#pragma unroll
  for (int mt = 0; mt < 2; ++mt)
#pragma unroll
    for (int j = 0; j < 4; ++j) {
      float l = lrun[mt][j];
      l += __shfl_xor(l, 1);
      l += __shfl_xor(l, 2);
      l += __shfl_xor(l, 4);
      l += __shfl_xor(l, 8);
      float inv = 1.f / l;
      int row = mt * 16 + g * 4 + j;
#pragma unroll
      for (int dd = 0; dd < 4; ++dd)
        ob[(size_t)row * D + dd * 16 + c] = acc[mt][dd][j] * inv;
    }
}

extern "C" void kernel_launch(void* const* d_in, const int* in_sizes, int n_in,
                              void* d_out, int out_size, void* d_ws, size_t ws_size,
                              hipStream_t stream) {
  const float* q  = (const float*)d_in[0];
  const float* k  = (const float*)d_in[1];
  const float* v  = (const float*)d_in[2];
  const float* am = (const float*)d_in[3];
  const float* sk = (const float*)d_in[4];
  const float* sv = (const float*)d_in[5];
  const float* sm = (const float*)d_in[6];
  const float* gk = (const float*)d_in[7];
  const float* gv = (const float*)d_in[8];
  const float* gm = (const float*)d_in[9];
  float* out = (float*)d_out;

  size_t off = 0;
  char* base = (char*)d_ws;
  auto alloc = [&](size_t bytes) { void* p = base + off; off += bytes; return p; };
  short* KL  = (short*)alloc(13369344);  // [24][4352][64] bf16
  short* VTL = (short*)alloc(13369344);  // [24][64][4352]
  short* KS  = (short*)alloc(4128768);   // [24][1344][64]
  short* VTS = (short*)alloc(4128768);   // [24][64][1344]
  short* KG  = (short*)alloc(196608);    // [24][64][64]
  short* VTG = (short*)alloc(196608);    // [24][64][64]
  float* AM2 = (float*)alloc(34816);     // [2][4352]
  float* SM2 = (float*)alloc(10752);     // [2][1344]
  float* GM2 = (float*)alloc(512);       // [2][64]

  if (off <= ws_size) {
    // conv_fused grid: (835584 + 258048 + 12288 + 11520) / 256 = 4365
    hipLaunchKernelGGL(conv_fused, dim3(4365), dim3(256), 0, stream,
                       k, sk, gk, KL, KS, KG, am, sm, gm, AM2, SM2, GM2);
    // transv_fused grid: 24*68 + 24*21 + 24 = 2160
    hipLaunchKernelGGL(transv_fused, dim3(2160), dim3(256), 0, stream,
                       v, sv, gv, VTL, VTS, VTG);
    hipLaunchKernelGGL(lsg_attn5, dim3(768), dim3(512), 0, stream,
                       KL, VTL, KS, VTS, KG, VTG, AM2, SM2, GM2, q, out);
  } else {
    hipLaunchKernelGGL(lsg_attn_fb, dim3(768), dim3(256), 0, stream,
                       q, k, v, am, sk, sv, sm, gk, gv, gm, out);
  }
}

// Round 10
// 58.559 us; speedup vs baseline: 3.9492x; 1.0165x over previous
//
#include <hip/hip_runtime.h>
#include <hip/hip_bf16.h>

typedef __attribute__((ext_vector_type(8))) short short8;
typedef __attribute__((ext_vector_type(4))) float f32x4;

#define LOG2E 1.44269504f
#define SCL2  0.18033688f   // 0.125 * log2(e)
#define MNEG  -3.0e38f
#define MINIT -1.0e30f

__device__ __forceinline__ short f2bf(float f) {
  union { float f; unsigned u; } x; x.f = f;
  return (short)((x.u + 0x7FFFu + ((x.u >> 16) & 1u)) >> 16);  // RNE
}
__device__ __forceinline__ float exp2g(float x) {
  float r; asm("v_exp_f32 %0, %1" : "=v"(r) : "v"(x)); return r;
}
__device__ __forceinline__ unsigned cvt_pk_bf16(float lo, float hi) {
  unsigned r;
  asm("v_cvt_pk_bf16_f32 %0, %1, %2" : "=v"(r) : "v"(lo), "v"(hi));
  return r;
}

// ---------------- fused prepass: K conv x3 | V transpose x3 | masks ---------
__device__ __forceinline__ void conv_one(
    const float* __restrict__ src, short* __restrict__ dst,
    int Tin, int pad, int cid) {
  int Tpad = Tin + 2 * pad;
  int row = cid >> 3;
  int d0 = (cid & 7) * 8;
  int tok = row % Tpad;
  int nh = row / Tpad;
  int st = tok - pad;
  short8 o;
  if (st >= 0 && st < Tin) {
    const float4* sp = (const float4*)(src + ((size_t)nh * Tin + st) * 64 + d0);
    float4 f0 = sp[0], f1 = sp[1];
    o[0] = f2bf(f0.x); o[1] = f2bf(f0.y); o[2] = f2bf(f0.z); o[3] = f2bf(f0.w);
    o[4] = f2bf(f1.x); o[5] = f2bf(f1.y); o[6] = f2bf(f1.z); o[7] = f2bf(f1.w);
  } else {
#pragma unroll
    for (int j = 0; j < 8; ++j) o[j] = 0;
  }
  *(short8*)(dst + (size_t)row * 64 + d0) = o;
}

__device__ __forceinline__ void transv_one(
    const float* __restrict__ src, short* __restrict__ dst,
    int Tin, int pad, int tiles, int bidx, int tid, short (*lt)[72]) {
  int tile = bidx % tiles;
  int nh = bidx / tiles;
  int Tpad = Tin + 2 * pad;
  int c0 = tile * 64;
  int tok = tid >> 2;
  int dc = (tid & 3) * 16;
  int st = c0 + tok - pad;
  if (st >= 0 && st < Tin) {
    const float4* sp = (const float4*)(src + ((size_t)nh * Tin + st) * 64 + dc);
#pragma unroll
    for (int i = 0; i < 4; ++i) {
      float4 f = sp[i];
      lt[tok][dc + i * 4 + 0] = f2bf(f.x);
      lt[tok][dc + i * 4 + 1] = f2bf(f.y);
      lt[tok][dc + i * 4 + 2] = f2bf(f.z);
      lt[tok][dc + i * 4 + 3] = f2bf(f.w);
    }
  } else {
#pragma unroll
    for (int i = 0; i < 16; ++i) lt[tok][dc + i] = 0;
  }
  __syncthreads();
  int d = tid >> 2;
  int tc = (tid & 3) * 16;
  short8 o0, o1;
#pragma unroll
  for (int j = 0; j < 8; ++j) { o0[j] = lt[tc + j][d]; o1[j] = lt[tc + 8 + j][d]; }
  short* dp = dst + ((size_t)nh * 64 + d) * Tpad + c0 + tc;
  *(short8*)(dp) = o0;
  *(short8*)(dp + 8) = o1;
}

// block ranges: [0,3264) KL | +1008 KS | +48 KG | +1632 VTL | +504 VTS |
//               +24 VTG | +45 masks  => grid 6525
__global__ __launch_bounds__(256) void prepass_all(
    const float* __restrict__ K, const float* __restrict__ SK,
    const float* __restrict__ GK,
    const float* __restrict__ V, const float* __restrict__ SV,
    const float* __restrict__ GV,
    short* __restrict__ KL, short* __restrict__ KS, short* __restrict__ KG,
    short* __restrict__ VTL, short* __restrict__ VTS, short* __restrict__ VTG,
    const float* __restrict__ am, const float* __restrict__ sm,
    const float* __restrict__ gm,
    float* __restrict__ AM2, float* __restrict__ SM2, float* __restrict__ GM2) {
  __shared__ short lt[64][72];
  int bidx = blockIdx.x;
  int tid = threadIdx.x;
  if (bidx < 3264) { conv_one(K,  KL, 4096, 128, bidx * 256 + tid); return; }
  bidx -= 3264;
  if (bidx < 1008) { conv_one(SK, KS, 1024, 160, bidx * 256 + tid); return; }
  bidx -= 1008;
  if (bidx < 48)   { conv_one(GK, KG, 64, 0, bidx * 256 + tid); return; }
  bidx -= 48;
  if (bidx < 1632) { transv_one(V,  VTL, 4096, 128, 68, bidx, tid, lt); return; }
  bidx -= 1632;
  if (bidx < 504)  { transv_one(SV, VTS, 1024, 160, 21, bidx, tid, lt); return; }
  bidx -= 504;
  if (bidx < 24)   { transv_one(GV, VTG, 64, 0, 1, bidx, tid, lt); return; }
  bidx -= 24;
  int i = bidx * 256 + tid;   // mask work: 11520 elements exactly
  if (i < 2 * 4352) {
    int n = i / 4352, rr = i % 4352, s = rr - 128;
    AM2[i] = (s >= 0 && s < 4096) ? am[n * 4096 + s] * LOG2E : MNEG;
  } else if (i < 2 * 4352 + 2 * 1344) {
    int j = i - 2 * 4352;
    int n = j / 1344, rr = j % 1344, s = rr - 160;
    SM2[j] = (s >= 0 && s < 1024) ? sm[n * 1024 + s] * LOG2E : MNEG;
  } else {
    int j = i - 2 * 4352 - 2 * 1344;
    GM2[j] = gm[j] * LOG2E;
  }
}

// ---------------- main attention kernel (8 waves, swizzled LDS) -------------
// Round-7 proven hot loop (reg staging + ds_write, lgkmcnt-only barrier,
// XOR-swizzled K/V LDS) + dead-tile skip via 4-bit packed tile list `enc`.
// One workgroup per (n,h,block); wave w owns queries [w*16, w*16+16).
// K rows in LDS key-interleaved: row r <- src key 4*(r&15)+(r>>4).
// K/V LDS: [64 rows][128 B], byte = row*128 + (col16 ^ ((row&7)<<4)) on both
// write and read -> staging writes conflict-free, reads 2-way (free).
// Tile liveness (derived from padded valid ranges; sparse [160,1184),
// local [128,4224)): t1: b>=4 | t2: b>=2 | t3: b<=29 | t4: b<=27 |
// t5,t6: b>=1 | t7,t8: always | t9,t10: b<=30 (dead ONLY at b=31).
__global__ __launch_bounds__(512, 4) void lsg_attn8(
    const short* __restrict__ KL, const short* __restrict__ VTL,
    const short* __restrict__ KS, const short* __restrict__ VTS,
    const short* __restrict__ KG, const short* __restrict__ VTG,
    const float* __restrict__ AM2, const float* __restrict__ SM2,
    const float* __restrict__ GM2,
    const float* __restrict__ q_, float* __restrict__ out) {
  constexpr int TPL = 4352, TPS = 1344;
  __shared__ __align__(16) char smem[49152];   // K dbuf 16K | V dbuf 16K | P 16K

  int bid = blockIdx.x;
  bid = (bid & 7) * 96 + (bid >> 3);        // XCD-contiguous logical ids
  const int b = bid & 31, nh = bid >> 5, n_ = nh / 12;
  const int tid = threadIdx.x;
  const int wid = tid >> 6, lane = tid & 63;
  const int c = lane & 15, g = lane >> 4;
  const int r = tid >> 3, ch = tid & 7;     // staging: 64 rows x 8 chunks(16B)
  const int skey = 4 * (r & 15) + (r >> 4); // interleaved K source key for row r
  char* pbase = smem + 32768 + wid * 2048;  // per-wave P [16][64] bf16
  const unsigned stg = ((unsigned)r << 7) + ((unsigned)(ch * 16) ^ ((unsigned)(r & 7) << 4));

  // ---- tile list: live tiles only, 4 bits per entry ----
  unsigned long long enc = 0; int nt = 0;
  {
    auto push = [&](int t) { enc |= (unsigned long long)t << (4 * nt); ++nt; };
    push(0);
    if (b >= 4)  push(1);
    if (b >= 2)  push(2);
    if (b <= 29) push(3);
    if (b <= 27) push(4);
    if (b >= 1)  { push(5); push(6); }
    push(7); push(8);
    if (b <= 30) { push(9); push(10); }   // FIXED: dead only at b==31
  }

  // ---- Q fragments: wave's 16 rows ----
  const float* qb = q_ + ((size_t)nh * 4096 + (size_t)b * 128 + wid * 16) * 64;
  short8 qa[2];
#pragma unroll
  for (int kc = 0; kc < 2; ++kc) {
    const float* qp = qb + (size_t)c * 64 + kc * 32 + g * 8;
    float4 f0 = *(const float4*)(qp);
    float4 f1 = *(const float4*)(qp + 4);
    short8 tq;
    tq[0] = f2bf(f0.x); tq[1] = f2bf(f0.y); tq[2] = f2bf(f0.z); tq[3] = f2bf(f0.w);
    tq[4] = f2bf(f1.x); tq[5] = f2bf(f1.y); tq[6] = f2bf(f1.z); tq[7] = f2bf(f1.w);
    qa[kc] = tq;
  }

  f32x4 acc[4];
  float mrun[4], lrun[4];
#pragma unroll
  for (int dd = 0; dd < 4; ++dd) acc[dd] = f32x4{0.f, 0.f, 0.f, 0.f};
#pragma unroll
  for (int j = 0; j < 4; ++j) { mrun[j] = MINIT; lrun[j] = 0.f; }

  auto src_for = [&](int t, const short*& kp, const short*& vp,
                     const float*& mp, int& stride) {
    if (t == 0) {
      kp = KG + (size_t)nh * (64 * 64);
      vp = VTG + (size_t)nh * (64 * 64);
      mp = GM2 + n_ * 64;
      stride = 64;
    } else if (t <= 4) {
      int r0 = b * 32 + (t - 1) * 64 + (t >= 3 ? 96 : 0);
      kp = KS + ((size_t)nh * TPS + r0) * 64;
      vp = VTS + (size_t)nh * (64 * TPS) + r0;
      mp = SM2 + n_ * TPS + r0;
      stride = TPS;
    } else {
      int r0 = b * 128 + (t - 5) * 64;
      kp = KL + ((size_t)nh * TPL + r0) * 64;
      vp = VTL + (size_t)nh * (64 * TPL) + r0;
      mp = AM2 + n_ * TPL + r0;
      stride = TPL;
    }
  };

  short8 kr, vr;
  float m_cur[4], m_nxt[4];

  // ---- prologue: tile[0] -> buf0; tile[1] -> regs; tile[0] masks ----
  {
    const short* kp; const short* vp; const float* mp; int st;
    src_for(0, kp, vp, mp, st);
    kr = *(const short8*)(kp + skey * 64 + ch * 8);
    vr = *(const short8*)(vp + (size_t)r * st + ch * 8);
#pragma unroll
    for (int i = 0; i < 4; ++i) m_cur[i] = mp[4 * c + i];
    *(short8*)(smem + stg) = kr;
    *(short8*)(smem + 16384 + stg) = vr;
    src_for((int)((enc >> 4) & 15ull), kp, vp, mp, st);   // nt >= 7 always
    kr = *(const short8*)(kp + skey * 64 + ch * 8);
    vr = *(const short8*)(vp + (size_t)r * st + ch * 8);
  }

  for (int i = 0; i < nt; ++i) {
    // own LDS ops drained, then workgroup barrier; vmcnt NOT drained
    asm volatile("s_waitcnt lgkmcnt(0)\n\ts_barrier" ::: "memory");
    const int cur = i & 1, nxt = cur ^ 1;
    char* kbuf = smem + cur * 8192;
    char* vbuf = smem + 16384 + cur * 8192;

    // ---- 1. QK^T K-fragment reads first (longest latency to MFMA) ----
    short8 bk[4][2];
#pragma unroll
    for (int kt = 0; kt < 4; ++kt)
#pragma unroll
      for (int kc = 0; kc < 2; ++kc) {
        unsigned off = ((unsigned)(kt * 16 + c) << 7) +
                       ((unsigned)(kc * 64 + g * 16) ^ ((unsigned)(c & 7) << 4));
        bk[kt][kc] = *(const short8*)(kbuf + off);
      }

    // ---- 2. write staged tile[i+1] ----
    if (i + 1 < nt) {
      *(short8*)(smem + nxt * 8192 + stg) = kr;
      *(short8*)(smem + 16384 + nxt * 8192 + stg) = vr;
    }
    // ---- 3. prefetch tile[i+2] into regs ----
    if (i + 2 < nt) {
      int tn = (int)((enc >> (4 * (i + 2))) & 15ull);
      const short* kp; const short* vp; const float* mp; int st;
      src_for(tn, kp, vp, mp, st);
      kr = *(const short8*)(kp + skey * 64 + ch * 8);
      vr = *(const short8*)(vp + (size_t)r * st + ch * 8);
    }
    if (i + 1 < nt) {   // tile[i+1] masks
      int tn = (int)((enc >> (4 * (i + 1))) & 15ull);
      const short* kp; const short* vp; const float* mp; int st;
      src_for(tn, kp, vp, mp, st);
#pragma unroll
      for (int j = 0; j < 4; ++j) m_nxt[j] = mp[4 * c + j];
    }

    // ---- QK^T: 16q x 64k ----
    f32x4 s4[4];
    __builtin_amdgcn_s_setprio(1);
#pragma unroll
    for (int kt = 0; kt < 4; ++kt) {
      f32x4 z = f32x4{0.f, 0.f, 0.f, 0.f};
      z = __builtin_amdgcn_mfma_f32_16x16x32_bf16(qa[0], bk[kt][0], z, 0, 0, 0);
      z = __builtin_amdgcn_mfma_f32_16x16x32_bf16(qa[1], bk[kt][1], z, 0, 0, 0);
      s4[kt] = z;
    }
    __builtin_amdgcn_s_setprio(0);
#pragma unroll
    for (int kt = 0; kt < 4; ++kt)
#pragma unroll
      for (int j = 0; j < 4; ++j)
        s4[kt][j] = fmaf(s4[kt][j], SCL2, m_cur[kt]);

    // ---- softmax pass 1 (optimistic, defer-max) ----
    float rs[4];
    float worst = 0.f;
#pragma unroll
    for (int j = 0; j < 4; ++j) {
      float mo = mrun[j];
      float p0 = exp2g(s4[0][j] - mo);
      float p1 = exp2g(s4[1][j] - mo);
      float p2 = exp2g(s4[2][j] - mo);
      float p3 = exp2g(s4[3][j] - mo);
      rs[j] = (p0 + p1) + (p2 + p3);
      worst = fmaxf(worst, rs[j]);
      unsigned w0 = cvt_pk_bf16(p0, p1);
      unsigned w1 = cvt_pk_bf16(p2, p3);
      int row = 4 * g + j;
      unsigned bo = ((unsigned)row << 7) + ((unsigned)c << 3);
      bo ^= (unsigned)((row & 7) << 4);
      uint2 u; u.x = w0; u.y = w1;
      *(uint2*)(pbase + bo) = u;
    }

    if (__any(worst > 4096.f)) {   // first tile + rare genuine max growth
#pragma unroll
      for (int j = 0; j < 4; ++j) {
        float v0 = s4[0][j], v1 = s4[1][j];
        float v2 = s4[2][j], v3 = s4[3][j];
        float tv = fmaxf(fmaxf(v0, v1), fmaxf(v2, v3));
        tv = fmaxf(tv, __shfl_xor(tv, 1));
        tv = fmaxf(tv, __shfl_xor(tv, 2));
        tv = fmaxf(tv, __shfl_xor(tv, 4));
        tv = fmaxf(tv, __shfl_xor(tv, 8));
        float mo = mrun[j];
        float mn = fmaxf(mo, tv);
        float sc = exp2g(mo - mn);
#pragma unroll
        for (int dd = 0; dd < 4; ++dd) acc[dd][j] *= sc;
        float p0 = exp2g(v0 - mn), p1 = exp2g(v1 - mn);
        float p2 = exp2g(v2 - mn), p3 = exp2g(v3 - mn);
        lrun[j] = lrun[j] * sc + ((p0 + p1) + (p2 + p3));
        mrun[j] = mn;
        unsigned w0 = cvt_pk_bf16(p0, p1);
        unsigned w1 = cvt_pk_bf16(p2, p3);
        int row = 4 * g + j;
        unsigned bo = ((unsigned)row << 7) + ((unsigned)c << 3);
        bo ^= (unsigned)((row & 7) << 4);
        uint2 u; u.x = w0; u.y = w1;
        *(uint2*)(pbase + bo) = u;
      }
    } else {
#pragma unroll
      for (int j = 0; j < 4; ++j) lrun[j] += rs[j];
    }

    // ---- PV: acc += P(16x64) * V(64x64) ----
#pragma unroll
    for (int kk = 0; kk < 2; ++kk) {
      unsigned bo = ((unsigned)c << 7) + (unsigned)(kk * 64 + g * 16);
      bo ^= (unsigned)((c & 7) << 4);
      short8 pa = *(const short8*)(pbase + bo);
      __builtin_amdgcn_s_setprio(1);
#pragma unroll
      for (int dd = 0; dd < 4; ++dd) {
        unsigned voff = ((unsigned)(dd * 16 + c) << 7) +
                        ((unsigned)(kk * 64 + g * 16) ^ ((unsigned)(c & 7) << 4));
        short8 bv = *(const short8*)(vbuf + voff);
        acc[dd] = __builtin_amdgcn_mfma_f32_16x16x32_bf16(pa, bv, acc[dd], 0, 0, 0);
      }
      __builtin_amdgcn_s_setprio(0);
    }
#pragma unroll
    for (int j = 0; j < 4; ++j) m_cur[j] = m_nxt[j];
  }

  // ---- epilogue: reduce l, normalize, coalesce via LDS, dwordx4 stores ----
  float inv[4];
#pragma unroll
  for (int j = 0; j < 4; ++j) {
    float l = lrun[j];
    l += __shfl_xor(l, 1);
    l += __shfl_xor(l, 2);
    l += __shfl_xor(l, 4);
    l += __shfl_xor(l, 8);
    inv[j] = 1.f / l;
  }
  __syncthreads();   // all tiles done; whole LDS dead -> reuse as fp32 staging
  float* fst = (float*)smem + wid * (16 * 68);   // per-wave [16][68] fp32
#pragma unroll
  for (int j = 0; j < 4; ++j)
#pragma unroll
    for (int dd = 0; dd < 4; ++dd)
      fst[(4 * g + j) * 68 + dd * 16 + c] = acc[dd][j] * inv[j];
  int rr = lane >> 2, cc = lane & 3;
  const float* fs = (float*)smem + wid * (16 * 68) + rr * 68 + cc * 16;
  float* op = out + ((size_t)nh * 4096 + (size_t)b * 128 + wid * 16 + rr) * 64 + cc * 16;
#pragma unroll
  for (int i = 0; i < 4; ++i)
    *(float4*)(op + i * 4) = *(const float4*)(fs + i * 4);
}

// ---------------- fallback (round-1 kernel, used if ws too small) -----------
__global__ __launch_bounds__(256) void lsg_attn_fb(
    const float* __restrict__ q_,  const float* __restrict__ k_,
    const float* __restrict__ v_,  const float* __restrict__ amask,
    const float* __restrict__ sk,  const float* __restrict__ sv,
    const float* __restrict__ smk, const float* __restrict__ gk,
    const float* __restrict__ gv,  const float* __restrict__ gmk,
    float* __restrict__ out) {
  constexpr int T = 4096, D = 64, TS = 1024;
  constexpr float NEGF = -3.402823466e38f;
  __shared__ __align__(16) short k_lds[32][72];
  __shared__ __align__(16) short v_lds[64][40];
  __shared__ __align__(16) short p_lds[4][32][40];
  __shared__ float m_lds[32];
  const int bid = blockIdx.x;
  const int b = bid & 31, nh = bid >> 5, n_ = nh / 12;
  const int tid = threadIdx.x, wid = tid >> 6, lane = tid & 63;
  const int c = lane & 15, g = lane >> 4;
  const float* qb = q_ + ((size_t)nh * T + (size_t)b * 128) * D;
  const float* kb = k_ + (size_t)nh * T * D;
  const float* vb = v_ + (size_t)nh * T * D;
  const float* skb = sk + (size_t)nh * TS * D;
  const float* svb = sv + (size_t)nh * TS * D;
  const float* gkb = gk + (size_t)nh * 64 * D;
  const float* gvb = gv + (size_t)nh * 64 * D;
  const float* am = amask + (size_t)n_ * T;
  const float* sm = smk + (size_t)n_ * TS;
  const float* gm = gmk + (size_t)n_ * 64;
  short8 qa[2][2];
#pragma unroll
  for (int mt = 0; mt < 2; ++mt)
#pragma unroll
    for (int kc = 0; kc < 2; ++kc) {
      const float* qp = qb + (size_t)(wid * 32 + mt * 16 + c) * D + kc * 32 + g * 8;
      short8 t;
#pragma unroll
      for (int j = 0; j < 8; ++j) t[j] = f2bf(qp[j]);
      qa[mt][kc] = t;
    }
  f32x4 acc[2][4];
#pragma unroll
  for (int mt = 0; mt < 2; ++mt)
#pragma unroll
    for (int dd = 0; dd < 4; ++dd) acc[mt][dd] = f32x4{0.f, 0.f, 0.f, 0.f};
  float mrun[2][4], lrun[2][4];
#pragma unroll
  for (int mt = 0; mt < 2; ++mt)
#pragma unroll
    for (int j = 0; j < 4; ++j) { mrun[mt][j] = NEGF; lrun[mt][j] = 0.f; }
  const int key_local = tid >> 3;
  const int seg = tid & 7;
  const int d0 = seg * 8;
  for (int tile = 0; tile < 22; ++tile) {
    __syncthreads();
    {
      const int kk = tile * 32 + key_local;
      const float* ksrc; const float* vsrc; float mval; bool valid;
      if (kk < 64) {
        ksrc = gkb + kk * D; vsrc = gvb + kk * D; mval = gm[kk]; valid = true;
      } else if (kk < 320) {
        int s = b * 32 - 160 + (kk - 64) + ((kk >= 192) ? 96 : 0);
        valid = (s >= 0) && (s < TS);
        int sc2 = valid ? s : 0;
        ksrc = skb + sc2 * D; vsrc = svb + sc2 * D;
        mval = valid ? sm[sc2] : NEGF;
      } else {
        int tt = b * 128 - 128 + (kk - 320);
        valid = (tt >= 0) && (tt < T);
        int tc = valid ? tt : 0;
        ksrc = kb + tc * D; vsrc = vb + tc * D;
        mval = valid ? am[tc] : NEGF;
      }
      short8 k8; short v8[8];
      if (valid) {
#pragma unroll
        for (int j = 0; j < 8; ++j) { k8[j] = f2bf(ksrc[d0 + j]); v8[j] = f2bf(vsrc[d0 + j]); }
      } else {
#pragma unroll
        for (int j = 0; j < 8; ++j) { k8[j] = 0; v8[j] = 0; }
      }
      *(short8*)(&k_lds[key_local][d0]) = k8;
#pragma unroll
      for (int j = 0; j < 8; ++j) v_lds[d0 + j][key_local] = v8[j];
      if (seg == 0) m_lds[key_local] = mval;
    }
    __syncthreads();
    short8 bk[2][2];
#pragma unroll
    for (int kt = 0; kt < 2; ++kt)
#pragma unroll
      for (int kc = 0; kc < 2; ++kc)
        bk[kt][kc] = *(const short8*)(&k_lds[kt * 16 + c][kc * 32 + g * 8]);
    f32x4 s_[2][2];
#pragma unroll
    for (int mt = 0; mt < 2; ++mt)
#pragma unroll
      for (int kt = 0; kt < 2; ++kt) {
        f32x4 z = f32x4{0.f, 0.f, 0.f, 0.f};
        z = __builtin_amdgcn_mfma_f32_16x16x32_bf16(qa[mt][0], bk[kt][0], z, 0, 0, 0);
        z = __builtin_amdgcn_mfma_f32_16x16x32_bf16(qa[mt][1], bk[kt][1], z, 0, 0, 0);
        s_[mt][kt] = z;
      }
    const float msk0 = m_lds[c];
    const float msk1 = m_lds[16 + c];
#pragma unroll
    for (int mt = 0; mt < 2; ++mt) {
#pragma unroll
      for (int j = 0; j < 4; ++j) {
        float s0 = s_[mt][0][j] * 0.125f + msk0;
        float s1 = s_[mt][1][j] * 0.125f + msk1;
        float tv = fmaxf(s0, s1);
        tv = fmaxf(tv, __shfl_xor(tv, 1));
        tv = fmaxf(tv, __shfl_xor(tv, 2));
        tv = fmaxf(tv, __shfl_xor(tv, 4));
        tv = fmaxf(tv, __shfl_xor(tv, 8));
        float mold = mrun[mt][j];
        float mnew = fmaxf(mold, tv);
        float scale = __expf(mold - mnew);
        mrun[mt][j] = mnew;
        float p0 = __expf(s0 - mnew);
        float p1 = __expf(s1 - mnew);
        lrun[mt][j] = lrun[mt][j] * scale + p0 + p1;
#pragma unroll
        for (int dd = 0; dd < 4; ++dd) acc[mt][dd][j] *= scale;
        p_lds[wid][mt * 16 + g * 4 + j][c] = f2bf(p0);
        p_lds[wid][mt * 16 + g * 4 + j][16 + c] = f2bf(p1);
      }
    }
    __syncthreads();
#pragma unroll
    for (int mt = 0; mt < 2; ++mt) {
      short8 pa = *(const short8*)(&p_lds[wid][mt * 16 + c][g * 8]);
#pragma unroll
      for (int dd = 0; dd < 4; ++dd) {
        short8 bv = *(const short8*)(&v_lds[dd * 16 + c][g * 8]);
        acc[mt][dd] = __builtin_amdgcn_mfma_f32_16x16x32_bf16(pa, bv, acc[mt][dd], 0, 0, 0);
      }
    }
  }
  float* ob = out + ((size_t)nh * T + (size_t)b * 128 + (size_t)wid * 32) * D;
#pragma unroll
  for (int mt = 0; mt < 2; ++mt)
#pragma unroll
    for (int j = 0; j < 4; ++j) {
      float l = lrun[mt][j];
      l += __shfl_xor(l, 1);
      l += __shfl_xor(l, 2);
      l += __shfl_xor(l, 4);
      l += __shfl_xor(l, 8);
      float inv = 1.f / l;
      int row = mt * 16 + g * 4 + j;
#pragma unroll
      for (int dd = 0; dd < 4; ++dd)
        ob[(size_t)row * D + dd * 16 + c] = acc[mt][dd][j] * inv;
    }
}

extern "C" void kernel_launch(void* const* d_in, const int* in_sizes, int n_in,
                              void* d_out, int out_size, void* d_ws, size_t ws_size,
                              hipStream_t stream) {
  const float* q  = (const float*)d_in[0];
  const float* k  = (const float*)d_in[1];
  const float* v  = (const float*)d_in[2];
  const float* am = (const float*)d_in[3];
  const float* sk = (const float*)d_in[4];
  const float* sv = (const float*)d_in[5];
  const float* sm = (const float*)d_in[6];
  const float* gk = (const float*)d_in[7];
  const float* gv = (const float*)d_in[8];
  const float* gm = (const float*)d_in[9];
  float* out = (float*)d_out;

  size_t off = 0;
  char* base = (char*)d_ws;
  auto alloc = [&](size_t bytes) { void* p = base + off; off += bytes; return p; };
  short* KL  = (short*)alloc(13369344);  // [24][4352][64] bf16
  short* VTL = (short*)alloc(13369344);  // [24][64][4352]
  short* KS  = (short*)alloc(4128768);   // [24][1344][64]
  short* VTS = (short*)alloc(4128768);   // [24][64][1344]
  short* KG  = (short*)alloc(196608);    // [24][64][64]
  short* VTG = (short*)alloc(196608);    // [24][64][64]
  float* AM2 = (float*)alloc(34816);     // [2][4352]
  float* SM2 = (float*)alloc(10752);     // [2][1344]
  float* GM2 = (float*)alloc(512);       // [2][64]

  if (off <= ws_size) {
    hipLaunchKernelGGL(prepass_all, dim3(6525), dim3(256), 0, stream,
                       k, sk, gk, v, sv, gv, KL, KS, KG, VTL, VTS, VTG,
                       am, sm, gm, AM2, SM2, GM2);
    hipLaunchKernelGGL(lsg_attn8, dim3(768), dim3(512), 0, stream,
                       KL, VTL, KS, VTS, KG, VTG, AM2, SM2, GM2, q, out);
  } else {
    hipLaunchKernelGGL(lsg_attn_fb, dim3(768), dim3(256), 0, stream,
                       q, k, v, am, sk, sv, sm, gk, gv, gm, out);
  }
}